// Round 14
// baseline (289.562 us; speedup 1.0000x reference)
//
#include <hip/hip_runtime.h>
#include <hip/hip_bf16.h>

#define D 64
#define ED 32
#define NN 50000
#define EE 800000
#define NT64 (EE / 64)   // 12500 64-edge tiles, exact
#define NWN (NN / 16)    // 3125 16-node tiles, exact

#define PREP_N (4 * D * D + D * ED)          // 18432 prep elements
#define NB_PREP ((PREP_N + 255) / 256)       // 72
#define NB_ZERO ((NN / 4 + 255) / 256)       // 49  (NN % 4 == 0)
#define NB_NODE ((NWN + 3) / 4)              // 782
#define NB_HIST ((EE / 4 + 255) / 256)       // 782 (EE % 4 == 0)
#define NB_SCAN ((NN + 255) / 256)           // 196

typedef __attribute__((ext_vector_type(8))) short bf16x8;
typedef __attribute__((ext_vector_type(4))) float f32x4;
typedef __attribute__((ext_vector_type(4))) unsigned uint4v;
typedef __attribute__((ext_vector_type(4))) int int4v;

__device__ __forceinline__ short f2bf(float f) {
    __hip_bfloat16 h = __float2bfloat16(f);
    return *reinterpret_cast<short*>(&h);
}
__device__ __forceinline__ float bfhi2f(unsigned w) { return __uint_as_float(w & 0xFFFF0000u); }
__device__ __forceinline__ float bflo2f(unsigned w) { return __uint_as_float(w << 16); }
__device__ __forceinline__ unsigned packqv(float q, float v) {
    return (unsigned)(unsigned short)f2bf(q) | ((unsigned)(unsigned short)f2bf(v) << 16);
}

// Fused: weight prep + deg/gctr zeroing. Edge tables COLUMN-PERMUTED:
// table row j holds original W column 4*(j&15)+(j>>4), so agg's C-fragment
// (lane lr, reg h) maps to logical dim 4*lr+h -> 16B vector gathers.
__global__ void prep_zero(const float* __restrict__ Wk, const float* __restrict__ Wq,
                          const float* __restrict__ Wv, const float* __restrict__ Ws,
                          unsigned short* __restrict__ WnT,
                          unsigned short* __restrict__ WgT, unsigned short* __restrict__ WvT,
                          int* __restrict__ deg, int* __restrict__ gctr) {
    const int b = blockIdx.x;
    if (b == 0 && threadIdx.x == 0) *gctr = 0;
    if (b < NB_PREP) {
        const int i = b * 256 + threadIdx.x;
        if (i < 4 * D * D) {
            // node tables stay in natural layout (node_hist epilogue uses 16h+lr)
            const int m = i >> 12, col = (i >> 6) & 63, k = i & 63;
            const float* W = (m == 0) ? Ws : (m == 1) ? Wk : (m == 2) ? Wq : Wv;
            WnT[i] = (unsigned short)f2bf(W[k * D + col]);
        } else {
            const int j = i - 4 * D * D;
            if (j < D * ED) {
                const int c = j >> 5, k = j & 31;
                const int cp = 4 * (c & 15) + (c >> 4);     // permuted column
                const size_t off = (size_t)(D + k) * D + cp;
                WgT[j] = (unsigned short)f2bf(Wk[off] + Wq[off]);
                WvT[j] = (unsigned short)f2bf(Wv[off]);
            }
        }
    } else {
        const int i = (b - NB_PREP) * 256 + threadIdx.x;   // int4 index
        if (i < NN / 4) ((int4v*)deg)[i] = (int4v){0, 0, 0, 0};
    }
}

// Mega-kernel: node MFMA transforms (pre-packed WnT) + dst histogram.
__global__ __launch_bounds__(256, 4)
void node_hist(const float* __restrict__ x, const unsigned short* __restrict__ WnT,
               const float* __restrict__ bk, const float* __restrict__ bq,
               const float* __restrict__ bv, const float* __restrict__ bias,
               float* __restrict__ kx, unsigned* __restrict__ qv, float* __restrict__ out,
               const int* __restrict__ dstI, int* __restrict__ deg) {
    const int b = blockIdx.x;
    if (b >= NB_NODE) {
        const int t = (b - NB_NODE) * 256 + threadIdx.x;
        const int e = 4 * t;
        if (e + 4 <= EE) {
            const int4v d4 = __builtin_nontemporal_load((const int4v*)(dstI + e));
#pragma unroll
            for (int r = 0; r < 4; ++r) atomicAdd(&deg[d4[r]], 1);
        }
        return;
    }
    const int lane = threadIdx.x & 63;
    const int wid  = b * 4 + (threadIdx.x >> 6);
    if (wid >= NWN) return;
    const int lg = lane >> 4, lr = lane & 15;
    const int n0 = wid * 16;

    const float* xp = x + (size_t)(n0 + lr) * D + 8 * lg;
    const f32x4 x00 = *(const f32x4*)xp;
    const f32x4 x01 = *(const f32x4*)(xp + 4);
    const f32x4 x10 = *(const f32x4*)(xp + 32);
    const f32x4 x11 = *(const f32x4*)(xp + 36);
    bf16x8 af0, af1;
#pragma unroll
    for (int e = 0; e < 4; ++e) {
        af0[e] = f2bf(x00[e]); af0[e + 4] = f2bf(x01[e]);
        af1[e] = f2bf(x10[e]); af1[e + 4] = f2bf(x11[e]);
    }

    f32x4 acc[4], accQ[4];
#pragma unroll
    for (int m = 0; m < 4; ++m) {
        f32x4* A = (m == 2) ? accQ : acc;
#pragma unroll
        for (int h = 0; h < 4; ++h) {
            const bf16x8 b0 = *(const bf16x8*)(WnT + (size_t)(m * D + 16 * h + lr) * D + 8 * lg);
            const bf16x8 b1 = *(const bf16x8*)(WnT + (size_t)(m * D + 16 * h + lr) * D + 32 + 8 * lg);
            A[h] = __builtin_amdgcn_mfma_f32_16x16x32_bf16(af0, b0, (f32x4)(0.f), 0, 0, 0);
            A[h] = __builtin_amdgcn_mfma_f32_16x16x32_bf16(af1, b1, A[h], 0, 0, 0);
        }
        if (m == 0) {
#pragma unroll
            for (int r = 0; r < 4; ++r)
#pragma unroll
                for (int h = 0; h < 4; ++h)
                    out[(size_t)(n0 + 4 * lg + r) * D + 16 * h + lr] = acc[h][r] + bias[16 * h + lr];
        } else if (m == 1) {
#pragma unroll
            for (int r = 0; r < 4; ++r)
#pragma unroll
                for (int h = 0; h < 4; ++h)
                    kx[(size_t)(n0 + 4 * lg + r) * D + 16 * h + lr] = acc[h][r] + bk[16 * h + lr];
        } else if (m == 3) {
#pragma unroll
            for (int r = 0; r < 4; ++r)
#pragma unroll
                for (int h = 0; h < 4; ++h)
                    qv[(size_t)(n0 + 4 * lg + r) * D + 16 * h + lr] =
                        packqv(accQ[h][r] + bq[16 * h + lr], acc[h][r] + bv[16 * h + lr]);
        }
    }
}

// Exclusive scan with atomic global base (proven).
__global__ void k_scanA(const int* __restrict__ deg, int* __restrict__ off,
                        int* __restrict__ gctr) {
    __shared__ int s_tmp[256];
    __shared__ int s_base;
    const int t = threadIdx.x, i = blockIdx.x * 256 + t;
    const int v = (i < NN) ? deg[i] : 0;
    s_tmp[t] = v;
    __syncthreads();
    for (int d = 1; d < 256; d <<= 1) {
        const int add = (t >= d) ? s_tmp[t - d] : 0;
        __syncthreads();
        s_tmp[t] += add;
        __syncthreads();
    }
    if (t == 255) s_base = atomicAdd(gctr, s_tmp[255]);
    __syncthreads();
    if (i < NN) off[i] = s_base + s_tmp[t] - v;
}

// Scatter, 4 edges/thread (proven).
__global__ void k_scatter4(const int* __restrict__ srcI, const int* __restrict__ dstI,
                           int* __restrict__ off, unsigned long long* __restrict__ rec) {
    const int t = blockIdx.x * 256 + threadIdx.x;
    const int e = 4 * t;
    if (e + 4 > EE) return;
    const int4v s4 = __builtin_nontemporal_load((const int4v*)(srcI + e));
    const int4v d4 = __builtin_nontemporal_load((const int4v*)(dstI + e));
#pragma unroll
    for (int r = 0; r < 4; ++r) {
        const int s = s4[r], d = d4[r];
        const int p = atomicAdd(&off[d], 1);
        rec[p] = ((unsigned long long)(unsigned)(e + r) << 32)
               | (unsigned)(s | (d << 16));
    }
}

// Edge-parallel aggregation over dst-grouped edges.
// r13 structure; ONLY change: launch_bounds 3 -> 8 waves/EU (occupancy probe:
// 2nd arg empirically pins waves/EU; VGPR=60 fits the 64-reg cap at 8/EU).
__global__ __launch_bounds__(256, 8)
void agg_sorted(const unsigned* __restrict__ rec, const float* __restrict__ ea,
                const unsigned short* __restrict__ WgT, const unsigned short* __restrict__ WvT,
                const float* __restrict__ kx, const unsigned* __restrict__ qv,
                float* __restrict__ out) {
    const int lane = threadIdx.x & 63;
    const int wid  = blockIdx.x * 4 + (threadIdx.x >> 6);   // tile id, grid exact
    const int lg = lane >> 4;
    const int lr = lane & 15;
    const int e0 = wid * 64;

    bf16x8 bg[4], bvf[4];
#pragma unroll
    for (int h = 0; h < 4; ++h) {
        bg[h]  = *(const bf16x8*)(WgT + (size_t)(16 * h + lr) * ED + 8 * lg);
        bvf[h] = *(const bf16x8*)(WvT + (size_t)(16 * h + lr) * ED + 8 * lg);
    }

#pragma unroll
    for (int g = 0; g < 4; ++g) {
        const int gb = e0 + 16 * g;
        const uint4v rA = *(const uint4v*)(rec + 2 * (gb + 4 * lg));
        const uint4v rB = *(const uint4v*)(rec + 2 * (gb + 4 * lg) + 4);
        int dR[4], sR[4];
        dR[0] = (int)(rA.x >> 16); sR[0] = (int)(rA.x & 0xFFFFu);
        dR[1] = (int)(rA.z >> 16); sR[1] = (int)(rA.z & 0xFFFFu);
        dR[2] = (int)(rB.x >> 16); sR[2] = (int)(rB.x & 0xFFFFu);
        dR[3] = (int)(rB.z >> 16); sR[3] = (int)(rB.z & 0xFFFFu);

        const unsigned pl = rec[2 * (gb + lr) + 1];
        const float* ap = ea + (size_t)pl * ED + 8 * lg;
        const f32x4 a0 = __builtin_nontemporal_load((const f32x4*)ap);
        const f32x4 a1 = __builtin_nontemporal_load((const f32x4*)(ap + 4));

        // vector gathers: per C-row one uint4 (qv) + one f32x4 (kx), dims 4lr..+3
        uint4v qd[4];
        f32x4  kd[4];
#pragma unroll
        for (int r = 0; r < 4; ++r) {
            qd[r] = *(const uint4v*)(qv + (size_t)sR[r] * D + 4 * lr);
            kd[r] = *(const f32x4*)(kx + (size_t)dR[r] * D + 4 * lr);
        }

        bf16x8 af;
#pragma unroll
        for (int e2 = 0; e2 < 4; ++e2) { af[e2] = f2bf(a0[e2]); af[e2 + 4] = f2bf(a1[e2]); }

        f32x4 accG[4], accV[4];
#pragma unroll
        for (int h = 0; h < 4; ++h) {
            accG[h] = __builtin_amdgcn_mfma_f32_16x16x32_bf16(af, bg[h],  (f32x4)(0.f), 0, 0, 0);
            accV[h] = __builtin_amdgcn_mfma_f32_16x16x32_bf16(af, bvf[h], (f32x4)(0.f), 0, 0, 0);
        }

        // msg[r][h]: edge gb+4lg+r, logical dim 4lr+h
        float msg[4][4];
#pragma unroll
        for (int r = 0; r < 4; ++r)
#pragma unroll
            for (int h = 0; h < 4; ++h) {
                const float z = accG[h][r] + kd[r][h] + bflo2f(qd[r][h]);
                const float v = accV[h][r] + bfhi2f(qd[r][h]);
                msg[r][h] = v * __builtin_amdgcn_rcpf(1.0f + __expf(-z));
            }

        bool done[4] = {false, false, false, false};
        while (true) {
            int m0 = 0x7FFFFFFF;
#pragma unroll
            for (int r = 0; r < 4; ++r) m0 = min(m0, done[r] ? 0x7FFFFFFF : dR[r]);
            m0 = min(m0, __shfl_xor(m0, 16, 64));
            m0 = min(m0, __shfl_xor(m0, 32, 64));
            if (m0 == 0x7FFFFFFF) break;          // wave-uniform exit
            float sh[4];
#pragma unroll
            for (int h = 0; h < 4; ++h) {
                float a = 0.f;
#pragma unroll
                for (int r = 0; r < 4; ++r) a += (dR[r] == m0) ? msg[r][h] : 0.f;
                a += __shfl_xor(a, 16, 64);
                a += __shfl_xor(a, 32, 64);
                sh[h] = a;        // every lane: run-total for dim 4*(lane&15)+h
            }
#pragma unroll
            for (int r = 0; r < 4; ++r) done[r] = done[r] || (dR[r] == m0);
            // transpose: lane j takes dim j = 4*(j>>2) + (j&3)
            const int qsrc = lane >> 2;
            const float t0 = __shfl(sh[0], qsrc, 64);
            const float t1 = __shfl(sh[1], qsrc, 64);
            const float t2 = __shfl(sh[2], qsrc, 64);
            const float t3 = __shfl(sh[3], qsrc, 64);
            const int hs = lane & 3;
            const float val = (hs == 0) ? t0 : (hs == 1) ? t1 : (hs == 2) ? t2 : t3;
            // one contiguous 256B wave-atomic per run
            unsafeAtomicAdd(&out[(size_t)m0 * D + lane], val);
        }
    }
}

extern "C" void kernel_launch(void* const* d_in, const int* in_sizes, int n_in,
                              void* d_out, int out_size, void* d_ws, size_t ws_size,
                              hipStream_t stream) {
    const float* x    = (const float*)d_in[0];
    const int*   eidx = (const int*)d_in[1];      // [2, E]: row0=src, row1=dst
    const float* eatt = (const float*)d_in[2];
    const float* Wk   = (const float*)d_in[3];
    const float* bk   = (const float*)d_in[4];
    const float* Wq   = (const float*)d_in[5];
    const float* bq   = (const float*)d_in[6];
    const float* Wv   = (const float*)d_in[7];
    const float* bv   = (const float*)d_in[8];
    const float* Ws   = (const float*)d_in[9];
    const float* bias = (const float*)d_in[10];
    float* out = (float*)d_out;

    // workspace carve (offsets keep 16B alignment)
    char* w = (char*)d_ws;
    float*    kx  = (float*)w;            w += (size_t)NN * D * 4;   // 12.8 MB
    unsigned* qv  = (unsigned*)w;         w += (size_t)NN * D * 4;   // 12.8 MB
    unsigned short* WnT = (unsigned short*)w;  w += 4 * D * D * 2;   // 32 KB
    unsigned short* WgT = (unsigned short*)w;  w += D * ED * 2;      // 4 KB
    unsigned short* WvT = (unsigned short*)w;  w += D * ED * 2;      // 4 KB
    int* deg  = (int*)w;                  w += (size_t)NN * 4;       // 200 KB
    int* gctr = (int*)w;                  w += 16;                   // 16 B
    int* off  = (int*)w;                  w += (size_t)NN * 4;       // 200 KB
    unsigned long long* rec = (unsigned long long*)w;                // 6.4 MB

    const int* srcI = eidx;
    const int* dstI = eidx + EE;

    // 1) weight prep + deg/gctr zero
    prep_zero<<<NB_PREP + NB_ZERO, 256, 0, stream>>>(Wk, Wq, Wv, Ws,
                                                     WnT, WgT, WvT, deg, gctr);
    // 2) node transforms + histogram
    node_hist<<<NB_NODE + NB_HIST, 256, 0, stream>>>(x, WnT, bk, bq, bv, bias,
                                                     kx, qv, out, dstI, deg);
    // 3) scan with atomic global base
    k_scanA<<<NB_SCAN, 256, 0, stream>>>(deg, off, gctr);
    // 4) scatter into dst-grouped records
    k_scatter4<<<NB_HIST, 256, 0, stream>>>(srcI, dstI, off, rec);
    // 5) aggregation
    agg_sorted<<<NT64 / 4, 256, 0, stream>>>((const unsigned*)rec, eatt,
                                             WgT, WvT, kx, qv, out);
}

// Round 15
// 187.945 us; speedup vs baseline: 1.5407x; 1.5407x over previous
//
#include <hip/hip_runtime.h>
#include <hip/hip_bf16.h>

#define D 64
#define ED 32
#define NN 50000
#define EE 800000
#define NT64 (EE / 64)   // 12500 64-edge tiles, exact
#define NWN (NN / 16)    // 3125 16-node tiles, exact

#define PREP_N (4 * D * D + D * ED)          // 18432 prep elements
#define NB_PREP ((PREP_N + 255) / 256)       // 72
#define NB_ZERO ((NN / 4 + 255) / 256)       // 49  (NN % 4 == 0)
#define NB_NODE ((NWN + 3) / 4)              // 782
#define NB_HIST ((EE / 4 + 255) / 256)       // 782 (EE % 4 == 0)
#define NB_SCAN ((NN + 255) / 256)           // 196

typedef __attribute__((ext_vector_type(8))) short bf16x8;
typedef __attribute__((ext_vector_type(4))) float f32x4;
typedef __attribute__((ext_vector_type(4))) unsigned uint4v;
typedef __attribute__((ext_vector_type(4))) int int4v;
typedef __attribute__((ext_vector_type(4))) unsigned short us4v;

__device__ __forceinline__ short f2bf(float f) {
    __hip_bfloat16 h = __float2bfloat16(f);
    return *reinterpret_cast<short*>(&h);
}
__device__ __forceinline__ float bfhi2f(unsigned w) { return __uint_as_float(w & 0xFFFF0000u); }
__device__ __forceinline__ float bflo2f(unsigned w) { return __uint_as_float(w << 16); }
__device__ __forceinline__ float us2f(unsigned short u) { return __uint_as_float(((unsigned)u) << 16); }
__device__ __forceinline__ unsigned packqv(float q, float v) {
    return (unsigned)(unsigned short)f2bf(q) | ((unsigned)(unsigned short)f2bf(v) << 16);
}

// Fused: weight prep + deg/gctr zeroing. Edge tables COLUMN-PERMUTED:
// table row j holds original W column 4*(j&15)+(j>>4) (r12/13 proven).
__global__ void prep_zero(const float* __restrict__ Wk, const float* __restrict__ Wq,
                          const float* __restrict__ Wv, const float* __restrict__ Ws,
                          unsigned short* __restrict__ WnT,
                          unsigned short* __restrict__ WgT, unsigned short* __restrict__ WvT,
                          int* __restrict__ deg, int* __restrict__ gctr) {
    const int b = blockIdx.x;
    if (b == 0 && threadIdx.x == 0) *gctr = 0;
    if (b < NB_PREP) {
        const int i = b * 256 + threadIdx.x;
        if (i < 4 * D * D) {
            const int m = i >> 12, col = (i >> 6) & 63, k = i & 63;
            const float* W = (m == 0) ? Ws : (m == 1) ? Wk : (m == 2) ? Wq : Wv;
            WnT[i] = (unsigned short)f2bf(W[k * D + col]);
        } else {
            const int j = i - 4 * D * D;
            if (j < D * ED) {
                const int c = j >> 5, k = j & 31;
                const int cp = 4 * (c & 15) + (c >> 4);     // permuted column
                const size_t off = (size_t)(D + k) * D + cp;
                WgT[j] = (unsigned short)f2bf(Wk[off] + Wq[off]);
                WvT[j] = (unsigned short)f2bf(Wv[off]);
            }
        }
    } else {
        const int i = (b - NB_PREP) * 256 + threadIdx.x;   // int4 index
        if (i < NN / 4) ((int4v*)deg)[i] = (int4v){0, 0, 0, 0};
    }
}

// Mega-kernel: node MFMA transforms + dst histogram. kx now stored as
// packed bf16 (kb, ushort/dim) to halve agg's k-gather bytes.
__global__ __launch_bounds__(256, 4)
void node_hist(const float* __restrict__ x, const unsigned short* __restrict__ WnT,
               const float* __restrict__ bk, const float* __restrict__ bq,
               const float* __restrict__ bv, const float* __restrict__ bias,
               unsigned short* __restrict__ kb, unsigned* __restrict__ qv,
               float* __restrict__ out,
               const int* __restrict__ dstI, int* __restrict__ deg) {
    const int b = blockIdx.x;
    if (b >= NB_NODE) {
        const int t = (b - NB_NODE) * 256 + threadIdx.x;
        const int e = 4 * t;
        if (e + 4 <= EE) {
            const int4v d4 = __builtin_nontemporal_load((const int4v*)(dstI + e));
#pragma unroll
            for (int r = 0; r < 4; ++r) atomicAdd(&deg[d4[r]], 1);
        }
        return;
    }
    const int lane = threadIdx.x & 63;
    const int wid  = b * 4 + (threadIdx.x >> 6);
    if (wid >= NWN) return;
    const int lg = lane >> 4, lr = lane & 15;
    const int n0 = wid * 16;

    const float* xp = x + (size_t)(n0 + lr) * D + 8 * lg;
    const f32x4 x00 = *(const f32x4*)xp;
    const f32x4 x01 = *(const f32x4*)(xp + 4);
    const f32x4 x10 = *(const f32x4*)(xp + 32);
    const f32x4 x11 = *(const f32x4*)(xp + 36);
    bf16x8 af0, af1;
#pragma unroll
    for (int e = 0; e < 4; ++e) {
        af0[e] = f2bf(x00[e]); af0[e + 4] = f2bf(x01[e]);
        af1[e] = f2bf(x10[e]); af1[e + 4] = f2bf(x11[e]);
    }

    f32x4 acc[4], accQ[4];
#pragma unroll
    for (int m = 0; m < 4; ++m) {
        f32x4* A = (m == 2) ? accQ : acc;
#pragma unroll
        for (int h = 0; h < 4; ++h) {
            const bf16x8 b0 = *(const bf16x8*)(WnT + (size_t)(m * D + 16 * h + lr) * D + 8 * lg);
            const bf16x8 b1 = *(const bf16x8*)(WnT + (size_t)(m * D + 16 * h + lr) * D + 32 + 8 * lg);
            A[h] = __builtin_amdgcn_mfma_f32_16x16x32_bf16(af0, b0, (f32x4)(0.f), 0, 0, 0);
            A[h] = __builtin_amdgcn_mfma_f32_16x16x32_bf16(af1, b1, A[h], 0, 0, 0);
        }
        if (m == 0) {
#pragma unroll
            for (int r = 0; r < 4; ++r)
#pragma unroll
                for (int h = 0; h < 4; ++h)
                    out[(size_t)(n0 + 4 * lg + r) * D + 16 * h + lr] = acc[h][r] + bias[16 * h + lr];
        } else if (m == 1) {
#pragma unroll
            for (int r = 0; r < 4; ++r)
#pragma unroll
                for (int h = 0; h < 4; ++h)
                    kb[(size_t)(n0 + 4 * lg + r) * D + 16 * h + lr] =
                        (unsigned short)f2bf(acc[h][r] + bk[16 * h + lr]);
        } else if (m == 3) {
#pragma unroll
            for (int r = 0; r < 4; ++r)
#pragma unroll
                for (int h = 0; h < 4; ++h)
                    qv[(size_t)(n0 + 4 * lg + r) * D + 16 * h + lr] =
                        packqv(accQ[h][r] + bq[16 * h + lr], acc[h][r] + bv[16 * h + lr]);
        }
    }
}

// Exclusive scan with atomic global base (proven).
__global__ void k_scanA(const int* __restrict__ deg, int* __restrict__ off,
                        int* __restrict__ gctr) {
    __shared__ int s_tmp[256];
    __shared__ int s_base;
    const int t = threadIdx.x, i = blockIdx.x * 256 + t;
    const int v = (i < NN) ? deg[i] : 0;
    s_tmp[t] = v;
    __syncthreads();
    for (int d = 1; d < 256; d <<= 1) {
        const int add = (t >= d) ? s_tmp[t - d] : 0;
        __syncthreads();
        s_tmp[t] += add;
        __syncthreads();
    }
    if (t == 255) s_base = atomicAdd(gctr, s_tmp[255]);
    __syncthreads();
    if (i < NN) off[i] = s_base + s_tmp[t] - v;
}

// Scatter, 4 edges/thread (proven).
__global__ void k_scatter4(const int* __restrict__ srcI, const int* __restrict__ dstI,
                           int* __restrict__ off, unsigned long long* __restrict__ rec) {
    const int t = blockIdx.x * 256 + threadIdx.x;
    const int e = 4 * t;
    if (e + 4 > EE) return;
    const int4v s4 = __builtin_nontemporal_load((const int4v*)(srcI + e));
    const int4v d4 = __builtin_nontemporal_load((const int4v*)(dstI + e));
#pragma unroll
    for (int r = 0; r < 4; ++r) {
        const int s = s4[r], d = d4[r];
        const int p = atomicAdd(&off[d], 1);
        rec[p] = ((unsigned long long)(unsigned)(e + r) << 32)
               | (unsigned)(s | (d << 16));
    }
}

// Edge-parallel aggregation (r13 structure). Changes: launch_bounds (256,4)
// (VGPR cap 128 > 60 live, occupancy 37->50%), kb gathers as 8B ushort4,
// and a tileBase param so the launch can be split for profiler visibility.
__global__ __launch_bounds__(256, 4)
void agg_sorted(const unsigned* __restrict__ rec, const float* __restrict__ ea,
                const unsigned short* __restrict__ WgT, const unsigned short* __restrict__ WvT,
                const unsigned short* __restrict__ kb, const unsigned* __restrict__ qv,
                float* __restrict__ out, int tileBase, int tileEnd) {
    const int lane = threadIdx.x & 63;
    const int wid  = tileBase + blockIdx.x * 4 + (threadIdx.x >> 6);
    if (wid >= tileEnd) return;
    const int lg = lane >> 4;
    const int lr = lane & 15;
    const int e0 = wid * 64;

    bf16x8 bg[4], bvf[4];
#pragma unroll
    for (int h = 0; h < 4; ++h) {
        bg[h]  = *(const bf16x8*)(WgT + (size_t)(16 * h + lr) * ED + 8 * lg);
        bvf[h] = *(const bf16x8*)(WvT + (size_t)(16 * h + lr) * ED + 8 * lg);
    }

#pragma unroll
    for (int g = 0; g < 4; ++g) {
        const int gb = e0 + 16 * g;
        const uint4v rA = *(const uint4v*)(rec + 2 * (gb + 4 * lg));
        const uint4v rB = *(const uint4v*)(rec + 2 * (gb + 4 * lg) + 4);
        int dR[4], sR[4];
        dR[0] = (int)(rA.x >> 16); sR[0] = (int)(rA.x & 0xFFFFu);
        dR[1] = (int)(rA.z >> 16); sR[1] = (int)(rA.z & 0xFFFFu);
        dR[2] = (int)(rB.x >> 16); sR[2] = (int)(rB.x & 0xFFFFu);
        dR[3] = (int)(rB.z >> 16); sR[3] = (int)(rB.z & 0xFFFFu);

        const unsigned pl = rec[2 * (gb + lr) + 1];
        const float* ap = ea + (size_t)pl * ED + 8 * lg;
        const f32x4 a0 = __builtin_nontemporal_load((const f32x4*)ap);
        const f32x4 a1 = __builtin_nontemporal_load((const f32x4*)(ap + 4));

        // vector gathers: per C-row one uint4 (qv, 16B) + one ushort4 (kb, 8B)
        uint4v qd[4];
        us4v   kd[4];
#pragma unroll
        for (int r = 0; r < 4; ++r) {
            qd[r] = *(const uint4v*)(qv + (size_t)sR[r] * D + 4 * lr);
            kd[r] = *(const us4v*)(kb + (size_t)dR[r] * D + 4 * lr);
        }

        bf16x8 af;
#pragma unroll
        for (int e2 = 0; e2 < 4; ++e2) { af[e2] = f2bf(a0[e2]); af[e2 + 4] = f2bf(a1[e2]); }

        f32x4 accG[4], accV[4];
#pragma unroll
        for (int h = 0; h < 4; ++h) {
            accG[h] = __builtin_amdgcn_mfma_f32_16x16x32_bf16(af, bg[h],  (f32x4)(0.f), 0, 0, 0);
            accV[h] = __builtin_amdgcn_mfma_f32_16x16x32_bf16(af, bvf[h], (f32x4)(0.f), 0, 0, 0);
        }

        // msg[r][h]: edge gb+4lg+r, logical dim 4lr+h
        float msg[4][4];
#pragma unroll
        for (int r = 0; r < 4; ++r)
#pragma unroll
            for (int h = 0; h < 4; ++h) {
                const float z = accG[h][r] + us2f(kd[r][h]) + bflo2f(qd[r][h]);
                const float v = accV[h][r] + bfhi2f(qd[r][h]);
                msg[r][h] = v * __builtin_amdgcn_rcpf(1.0f + __expf(-z));
            }

        bool done[4] = {false, false, false, false};
        while (true) {
            int m0 = 0x7FFFFFFF;
#pragma unroll
            for (int r = 0; r < 4; ++r) m0 = min(m0, done[r] ? 0x7FFFFFFF : dR[r]);
            m0 = min(m0, __shfl_xor(m0, 16, 64));
            m0 = min(m0, __shfl_xor(m0, 32, 64));
            if (m0 == 0x7FFFFFFF) break;          // wave-uniform exit
            float sh[4];
#pragma unroll
            for (int h = 0; h < 4; ++h) {
                float a = 0.f;
#pragma unroll
                for (int r = 0; r < 4; ++r) a += (dR[r] == m0) ? msg[r][h] : 0.f;
                a += __shfl_xor(a, 16, 64);
                a += __shfl_xor(a, 32, 64);
                sh[h] = a;        // every lane: run-total for dim 4*(lane&15)+h
            }
#pragma unroll
            for (int r = 0; r < 4; ++r) done[r] = done[r] || (dR[r] == m0);
            // transpose: lane j takes dim j = 4*(j>>2) + (j&3)
            const int qsrc = lane >> 2;
            const float t0 = __shfl(sh[0], qsrc, 64);
            const float t1 = __shfl(sh[1], qsrc, 64);
            const float t2 = __shfl(sh[2], qsrc, 64);
            const float t3 = __shfl(sh[3], qsrc, 64);
            const int hs = lane & 3;
            const float val = (hs == 0) ? t0 : (hs == 1) ? t1 : (hs == 2) ? t2 : t3;
            // one contiguous 256B wave-atomic per run
            unsafeAtomicAdd(&out[(size_t)m0 * D + lane], val);
        }
    }
}

extern "C" void kernel_launch(void* const* d_in, const int* in_sizes, int n_in,
                              void* d_out, int out_size, void* d_ws, size_t ws_size,
                              hipStream_t stream) {
    const float* x    = (const float*)d_in[0];
    const int*   eidx = (const int*)d_in[1];      // [2, E]: row0=src, row1=dst
    const float* eatt = (const float*)d_in[2];
    const float* Wk   = (const float*)d_in[3];
    const float* bk   = (const float*)d_in[4];
    const float* Wq   = (const float*)d_in[5];
    const float* bq   = (const float*)d_in[6];
    const float* Wv   = (const float*)d_in[7];
    const float* bv   = (const float*)d_in[8];
    const float* Ws   = (const float*)d_in[9];
    const float* bias = (const float*)d_in[10];
    float* out = (float*)d_out;

    // workspace carve (offsets keep 16B alignment)
    char* w = (char*)d_ws;
    unsigned short* kb = (unsigned short*)w;   w += (size_t)NN * D * 2;  // 6.4 MB
    unsigned* qv  = (unsigned*)w;              w += (size_t)NN * D * 4;  // 12.8 MB
    unsigned short* WnT = (unsigned short*)w;  w += 4 * D * D * 2;       // 32 KB
    unsigned short* WgT = (unsigned short*)w;  w += D * ED * 2;          // 4 KB
    unsigned short* WvT = (unsigned short*)w;  w += D * ED * 2;          // 4 KB
    int* deg  = (int*)w;                  w += (size_t)NN * 4;           // 200 KB
    int* gctr = (int*)w;                  w += 16;                       // 16 B
    int* off  = (int*)w;                  w += (size_t)NN * 4;           // 200 KB
    unsigned long long* rec = (unsigned long long*)w;                    // 6.4 MB

    const int* srcI = eidx;
    const int* dstI = eidx + EE;

    // 1) weight prep + deg/gctr zero
    prep_zero<<<NB_PREP + NB_ZERO, 256, 0, stream>>>(Wk, Wq, Wv, Ws,
                                                     WnT, WgT, WvT, deg, gctr);
    // 2) node transforms + histogram
    node_hist<<<NB_NODE + NB_HIST, 256, 0, stream>>>(x, WnT, bk, bq, bv, bias,
                                                     kb, qv, out, dstI, deg);
    // 3) scan with atomic global base
    k_scanA<<<NB_SCAN, 256, 0, stream>>>(deg, off, gctr);
    // 4) scatter into dst-grouped records
    k_scatter4<<<NB_HIST, 256, 0, stream>>>(srcI, dstI, off, rec);
    // 5) aggregation, split into two dispatches (profiler visibility for the
    //    build kernels; each half ~32us)
    const int HALF = NT64 / 2;                       // 6250 tiles
    agg_sorted<<<(HALF + 3) / 4, 256, 0, stream>>>((const unsigned*)rec, eatt,
                                                   WgT, WvT, kb, qv, out, 0, HALF);
    agg_sorted<<<(HALF + 3) / 4, 256, 0, stream>>>((const unsigned*)rec, eatt,
                                                   WgT, WvT, kb, qv, out, HALF, NT64);
}

// Round 16
// 179.470 us; speedup vs baseline: 1.6134x; 1.0472x over previous
//
#include <hip/hip_runtime.h>
#include <hip/hip_bf16.h>

#define D 64
#define ED 32
#define NN 50000
#define EE 800000
#define NT64 (EE / 64)   // 12500 64-edge tiles, exact
#define NWN (NN / 16)    // 3125 16-node tiles, exact

#define PREP_N (4 * D * D + D * ED)          // 18432 prep elements
#define NB_PREP ((PREP_N + 255) / 256)       // 72
#define NB_ZERO ((NN / 4 + 255) / 256)       // 49  (NN % 4 == 0)
#define NB_NODE ((NWN + 3) / 4)              // 782
#define NB_HIST ((EE / 4 + 255) / 256)       // 782 (EE % 4 == 0)
#define NB_SCAT (EE / 256)                   // 3125 (1 edge/thread)
#define NB_SCAN ((NN + 255) / 256)           // 196

typedef __attribute__((ext_vector_type(8))) short bf16x8;
typedef __attribute__((ext_vector_type(4))) float f32x4;
typedef __attribute__((ext_vector_type(4))) unsigned uint4v;
typedef __attribute__((ext_vector_type(4))) int int4v;
typedef __attribute__((ext_vector_type(4))) unsigned short us4v;

__device__ __forceinline__ short f2bf(float f) {
    __hip_bfloat16 h = __float2bfloat16(f);
    return *reinterpret_cast<short*>(&h);
}
__device__ __forceinline__ float bfhi2f(unsigned w) { return __uint_as_float(w & 0xFFFF0000u); }
__device__ __forceinline__ float bflo2f(unsigned w) { return __uint_as_float(w << 16); }
__device__ __forceinline__ float us2f(unsigned short u) { return __uint_as_float(((unsigned)u) << 16); }
__device__ __forceinline__ unsigned packqv(float q, float v) {
    return (unsigned)(unsigned short)f2bf(q) | ((unsigned)(unsigned short)f2bf(v) << 16);
}

// Fused: weight prep + deg/gctr zeroing. Edge tables COLUMN-PERMUTED:
// table row j holds original W column 4*(j&15)+(j>>4) (r12/13 proven).
__global__ void prep_zero(const float* __restrict__ Wk, const float* __restrict__ Wq,
                          const float* __restrict__ Wv, const float* __restrict__ Ws,
                          unsigned short* __restrict__ WnT,
                          unsigned short* __restrict__ WgT, unsigned short* __restrict__ WvT,
                          int* __restrict__ deg, int* __restrict__ gctr) {
    const int b = blockIdx.x;
    if (b == 0 && threadIdx.x == 0) *gctr = 0;
    if (b < NB_PREP) {
        const int i = b * 256 + threadIdx.x;
        if (i < 4 * D * D) {
            const int m = i >> 12, col = (i >> 6) & 63, k = i & 63;
            const float* W = (m == 0) ? Ws : (m == 1) ? Wk : (m == 2) ? Wq : Wv;
            WnT[i] = (unsigned short)f2bf(W[k * D + col]);
        } else {
            const int j = i - 4 * D * D;
            if (j < D * ED) {
                const int c = j >> 5, k = j & 31;
                const int cp = 4 * (c & 15) + (c >> 4);     // permuted column
                const size_t off = (size_t)(D + k) * D + cp;
                WgT[j] = (unsigned short)f2bf(Wk[off] + Wq[off]);
                WvT[j] = (unsigned short)f2bf(Wv[off]);
            }
        }
    } else {
        const int i = (b - NB_PREP) * 256 + threadIdx.x;   // int4 index
        if (i < NN / 4) ((int4v*)deg)[i] = (int4v){0, 0, 0, 0};
    }
}

// Mega-kernel: node MFMA transforms + dst histogram. kx stored as packed
// bf16 (kb) to halve agg's k-gather bytes (r15 proven).
__global__ __launch_bounds__(256, 4)
void node_hist(const float* __restrict__ x, const unsigned short* __restrict__ WnT,
               const float* __restrict__ bk, const float* __restrict__ bq,
               const float* __restrict__ bv, const float* __restrict__ bias,
               unsigned short* __restrict__ kb, unsigned* __restrict__ qv,
               float* __restrict__ out,
               const int* __restrict__ dstI, int* __restrict__ deg) {
    const int b = blockIdx.x;
    if (b >= NB_NODE) {
        const int t = (b - NB_NODE) * 256 + threadIdx.x;
        const int e = 4 * t;
        if (e + 4 <= EE) {
            const int4v d4 = __builtin_nontemporal_load((const int4v*)(dstI + e));
#pragma unroll
            for (int r = 0; r < 4; ++r) atomicAdd(&deg[d4[r]], 1);
        }
        return;
    }
    const int lane = threadIdx.x & 63;
    const int wid  = b * 4 + (threadIdx.x >> 6);
    if (wid >= NWN) return;
    const int lg = lane >> 4, lr = lane & 15;
    const int n0 = wid * 16;

    const float* xp = x + (size_t)(n0 + lr) * D + 8 * lg;
    const f32x4 x00 = *(const f32x4*)xp;
    const f32x4 x01 = *(const f32x4*)(xp + 4);
    const f32x4 x10 = *(const f32x4*)(xp + 32);
    const f32x4 x11 = *(const f32x4*)(xp + 36);
    bf16x8 af0, af1;
#pragma unroll
    for (int e = 0; e < 4; ++e) {
        af0[e] = f2bf(x00[e]); af0[e + 4] = f2bf(x01[e]);
        af1[e] = f2bf(x10[e]); af1[e + 4] = f2bf(x11[e]);
    }

    f32x4 acc[4], accQ[4];
#pragma unroll
    for (int m = 0; m < 4; ++m) {
        f32x4* A = (m == 2) ? accQ : acc;
#pragma unroll
        for (int h = 0; h < 4; ++h) {
            const bf16x8 b0 = *(const bf16x8*)(WnT + (size_t)(m * D + 16 * h + lr) * D + 8 * lg);
            const bf16x8 b1 = *(const bf16x8*)(WnT + (size_t)(m * D + 16 * h + lr) * D + 32 + 8 * lg);
            A[h] = __builtin_amdgcn_mfma_f32_16x16x32_bf16(af0, b0, (f32x4)(0.f), 0, 0, 0);
            A[h] = __builtin_amdgcn_mfma_f32_16x16x32_bf16(af1, b1, A[h], 0, 0, 0);
        }
        if (m == 0) {
#pragma unroll
            for (int r = 0; r < 4; ++r)
#pragma unroll
                for (int h = 0; h < 4; ++h)
                    out[(size_t)(n0 + 4 * lg + r) * D + 16 * h + lr] = acc[h][r] + bias[16 * h + lr];
        } else if (m == 1) {
#pragma unroll
            for (int r = 0; r < 4; ++r)
#pragma unroll
                for (int h = 0; h < 4; ++h)
                    kb[(size_t)(n0 + 4 * lg + r) * D + 16 * h + lr] =
                        (unsigned short)f2bf(acc[h][r] + bk[16 * h + lr]);
        } else if (m == 3) {
#pragma unroll
            for (int r = 0; r < 4; ++r)
#pragma unroll
                for (int h = 0; h < 4; ++h)
                    qv[(size_t)(n0 + 4 * lg + r) * D + 16 * h + lr] =
                        packqv(accQ[h][r] + bq[16 * h + lr], acc[h][r] + bv[16 * h + lr]);
        }
    }
}

// Exclusive scan with atomic global base (proven).
__global__ void k_scanA(const int* __restrict__ deg, int* __restrict__ off,
                        int* __restrict__ gctr) {
    __shared__ int s_tmp[256];
    __shared__ int s_base;
    const int t = threadIdx.x, i = blockIdx.x * 256 + t;
    const int v = (i < NN) ? deg[i] : 0;
    s_tmp[t] = v;
    __syncthreads();
    for (int d = 1; d < 256; d <<= 1) {
        const int add = (t >= d) ? s_tmp[t - d] : 0;
        __syncthreads();
        s_tmp[t] += add;
        __syncthreads();
    }
    if (t == 255) s_base = atomicAdd(gctr, s_tmp[255]);
    __syncthreads();
    if (i < NN) off[i] = s_base + s_tmp[t] - v;
}

// Scatter, ONE edge/thread: 3125 blocks (~12/CU) -> occupancy ~100% at
// VGPR=8, 4x the in-flight fetch-adds vs the 782-block 4-edge version
// (which was grid-capped at 28% occupancy and 63us, pure latency).
__global__ void k_scatter1(const int* __restrict__ srcI, const int* __restrict__ dstI,
                           int* __restrict__ off, unsigned long long* __restrict__ rec) {
    const int e = blockIdx.x * 256 + threadIdx.x;
    const int s = srcI[e], d = dstI[e];          // coalesced 4B loads
    const int p = atomicAdd(&off[d], 1);
    __builtin_nontemporal_store(
        ((unsigned long long)(unsigned)e << 32) | (unsigned)(s | (d << 16)),
        rec + p);
}

// Edge-parallel aggregation (r13 structure, r15 refinements: (256,4),
// kb as 8B ushort4 gathers, permuted-column C layout, transpose+256B atomic).
__global__ __launch_bounds__(256, 4)
void agg_sorted(const unsigned* __restrict__ rec, const float* __restrict__ ea,
                const unsigned short* __restrict__ WgT, const unsigned short* __restrict__ WvT,
                const unsigned short* __restrict__ kb, const unsigned* __restrict__ qv,
                float* __restrict__ out) {
    const int lane = threadIdx.x & 63;
    const int wid  = blockIdx.x * 4 + (threadIdx.x >> 6);   // tile id, grid exact
    const int lg = lane >> 4;
    const int lr = lane & 15;
    const int e0 = wid * 64;

    bf16x8 bg[4], bvf[4];
#pragma unroll
    for (int h = 0; h < 4; ++h) {
        bg[h]  = *(const bf16x8*)(WgT + (size_t)(16 * h + lr) * ED + 8 * lg);
        bvf[h] = *(const bf16x8*)(WvT + (size_t)(16 * h + lr) * ED + 8 * lg);
    }

#pragma unroll
    for (int g = 0; g < 4; ++g) {
        const int gb = e0 + 16 * g;
        const uint4v rA = *(const uint4v*)(rec + 2 * (gb + 4 * lg));
        const uint4v rB = *(const uint4v*)(rec + 2 * (gb + 4 * lg) + 4);
        int dR[4], sR[4];
        dR[0] = (int)(rA.x >> 16); sR[0] = (int)(rA.x & 0xFFFFu);
        dR[1] = (int)(rA.z >> 16); sR[1] = (int)(rA.z & 0xFFFFu);
        dR[2] = (int)(rB.x >> 16); sR[2] = (int)(rB.x & 0xFFFFu);
        dR[3] = (int)(rB.z >> 16); sR[3] = (int)(rB.z & 0xFFFFu);

        const unsigned pl = rec[2 * (gb + lr) + 1];
        const float* ap = ea + (size_t)pl * ED + 8 * lg;
        const f32x4 a0 = __builtin_nontemporal_load((const f32x4*)ap);
        const f32x4 a1 = __builtin_nontemporal_load((const f32x4*)(ap + 4));

        // vector gathers: per C-row one uint4 (qv, 16B) + one ushort4 (kb, 8B)
        uint4v qd[4];
        us4v   kd[4];
#pragma unroll
        for (int r = 0; r < 4; ++r) {
            qd[r] = *(const uint4v*)(qv + (size_t)sR[r] * D + 4 * lr);
            kd[r] = *(const us4v*)(kb + (size_t)dR[r] * D + 4 * lr);
        }

        bf16x8 af;
#pragma unroll
        for (int e2 = 0; e2 < 4; ++e2) { af[e2] = f2bf(a0[e2]); af[e2 + 4] = f2bf(a1[e2]); }

        f32x4 accG[4], accV[4];
#pragma unroll
        for (int h = 0; h < 4; ++h) {
            accG[h] = __builtin_amdgcn_mfma_f32_16x16x32_bf16(af, bg[h],  (f32x4)(0.f), 0, 0, 0);
            accV[h] = __builtin_amdgcn_mfma_f32_16x16x32_bf16(af, bvf[h], (f32x4)(0.f), 0, 0, 0);
        }

        // msg[r][h]: edge gb+4lg+r, logical dim 4lr+h
        float msg[4][4];
#pragma unroll
        for (int r = 0; r < 4; ++r)
#pragma unroll
            for (int h = 0; h < 4; ++h) {
                const float z = accG[h][r] + us2f(kd[r][h]) + bflo2f(qd[r][h]);
                const float v = accV[h][r] + bfhi2f(qd[r][h]);
                msg[r][h] = v * __builtin_amdgcn_rcpf(1.0f + __expf(-z));
            }

        bool done[4] = {false, false, false, false};
        while (true) {
            int m0 = 0x7FFFFFFF;
#pragma unroll
            for (int r = 0; r < 4; ++r) m0 = min(m0, done[r] ? 0x7FFFFFFF : dR[r]);
            m0 = min(m0, __shfl_xor(m0, 16, 64));
            m0 = min(m0, __shfl_xor(m0, 32, 64));
            if (m0 == 0x7FFFFFFF) break;          // wave-uniform exit
            float sh[4];
#pragma unroll
            for (int h = 0; h < 4; ++h) {
                float a = 0.f;
#pragma unroll
                for (int r = 0; r < 4; ++r) a += (dR[r] == m0) ? msg[r][h] : 0.f;
                a += __shfl_xor(a, 16, 64);
                a += __shfl_xor(a, 32, 64);
                sh[h] = a;        // every lane: run-total for dim 4*(lane&15)+h
            }
#pragma unroll
            for (int r = 0; r < 4; ++r) done[r] = done[r] || (dR[r] == m0);
            // transpose: lane j takes dim j = 4*(j>>2) + (j&3)
            const int qsrc = lane >> 2;
            const float t0 = __shfl(sh[0], qsrc, 64);
            const float t1 = __shfl(sh[1], qsrc, 64);
            const float t2 = __shfl(sh[2], qsrc, 64);
            const float t3 = __shfl(sh[3], qsrc, 64);
            const int hs = lane & 3;
            const float val = (hs == 0) ? t0 : (hs == 1) ? t1 : (hs == 2) ? t2 : t3;
            // one contiguous 256B wave-atomic per run
            unsafeAtomicAdd(&out[(size_t)m0 * D + lane], val);
        }
    }
}

extern "C" void kernel_launch(void* const* d_in, const int* in_sizes, int n_in,
                              void* d_out, int out_size, void* d_ws, size_t ws_size,
                              hipStream_t stream) {
    const float* x    = (const float*)d_in[0];
    const int*   eidx = (const int*)d_in[1];      // [2, E]: row0=src, row1=dst
    const float* eatt = (const float*)d_in[2];
    const float* Wk   = (const float*)d_in[3];
    const float* bk   = (const float*)d_in[4];
    const float* Wq   = (const float*)d_in[5];
    const float* bq   = (const float*)d_in[6];
    const float* Wv   = (const float*)d_in[7];
    const float* bv   = (const float*)d_in[8];
    const float* Ws   = (const float*)d_in[9];
    const float* bias = (const float*)d_in[10];
    float* out = (float*)d_out;

    // workspace carve (offsets keep 16B alignment)
    char* w = (char*)d_ws;
    unsigned short* kb = (unsigned short*)w;   w += (size_t)NN * D * 2;  // 6.4 MB
    unsigned* qv  = (unsigned*)w;              w += (size_t)NN * D * 4;  // 12.8 MB
    unsigned short* WnT = (unsigned short*)w;  w += 4 * D * D * 2;       // 32 KB
    unsigned short* WgT = (unsigned short*)w;  w += D * ED * 2;          // 4 KB
    unsigned short* WvT = (unsigned short*)w;  w += D * ED * 2;          // 4 KB
    int* deg  = (int*)w;                  w += (size_t)NN * 4;           // 200 KB
    int* gctr = (int*)w;                  w += 16;                       // 16 B
    int* off  = (int*)w;                  w += (size_t)NN * 4;           // 200 KB
    unsigned long long* rec = (unsigned long long*)w;                    // 6.4 MB

    const int* srcI = eidx;
    const int* dstI = eidx + EE;

    // 1) weight prep + deg/gctr zero
    prep_zero<<<NB_PREP + NB_ZERO, 256, 0, stream>>>(Wk, Wq, Wv, Ws,
                                                     WnT, WgT, WvT, deg, gctr);
    // 2) node transforms + histogram
    node_hist<<<NB_NODE + NB_HIST, 256, 0, stream>>>(x, WnT, bk, bq, bv, bias,
                                                     kb, qv, out, dstI, deg);
    // 3) scan with atomic global base
    k_scanA<<<NB_SCAN, 256, 0, stream>>>(deg, off, gctr);
    // 4) scatter into dst-grouped records (1 edge/thread, full occupancy)
    k_scatter1<<<NB_SCAT, 256, 0, stream>>>(srcI, dstI, off, rec);
    // 5) aggregation (single dispatch)
    agg_sorted<<<NT64 / 4, 256, 0, stream>>>((const unsigned*)rec, eatt,
                                             WgT, WvT, kb, qv, out);
}

// Round 17
// 163.939 us; speedup vs baseline: 1.7663x; 1.0947x over previous
//
#include <hip/hip_runtime.h>
#include <hip/hip_bf16.h>

#define D 64
#define ED 32
#define NN 50000
#define EE 800000
#define NT64 (EE / 64)   // 12500 64-edge tiles, exact
#define NWN (NN / 16)    // 3125 16-node tiles, exact

#define PREP_N (4 * D * D + D * ED)          // 18432 prep elements
#define NB_PREP ((PREP_N + 255) / 256)       // 72
#define NB_ZERO ((NN / 4 + 255) / 256)       // 49  (NN % 4 == 0)
#define NB_NODE ((NWN + 3) / 4)              // 782
#define NB_HIST ((EE / 4 + 255) / 256)       // 782 (EE % 4 == 0)
#define NB_SCAT (EE / 256)                   // 3125 (1 edge/thread)
#define NB_SCAN ((NN + 255) / 256)           // 196

typedef __attribute__((ext_vector_type(8))) short bf16x8;
typedef __attribute__((ext_vector_type(4))) float f32x4;
typedef __attribute__((ext_vector_type(4))) unsigned uint4v;
typedef __attribute__((ext_vector_type(4))) int int4v;
typedef __attribute__((ext_vector_type(4))) unsigned short us4v;

__device__ __forceinline__ short f2bf(float f) {
    __hip_bfloat16 h = __float2bfloat16(f);
    return *reinterpret_cast<short*>(&h);
}
__device__ __forceinline__ float bfhi2f(unsigned w) { return __uint_as_float(w & 0xFFFF0000u); }
__device__ __forceinline__ float bflo2f(unsigned w) { return __uint_as_float(w << 16); }
__device__ __forceinline__ float us2f(unsigned short u) { return __uint_as_float(((unsigned)u) << 16); }
__device__ __forceinline__ unsigned packqv(float q, float v) {
    return (unsigned)(unsigned short)f2bf(q) | ((unsigned)(unsigned short)f2bf(v) << 16);
}

// Fused: weight prep + deg/gctr zeroing. Edge tables COLUMN-PERMUTED:
// table row j holds original W column 4*(j&15)+(j>>4) (r12/13 proven).
__global__ void prep_zero(const float* __restrict__ Wk, const float* __restrict__ Wq,
                          const float* __restrict__ Wv, const float* __restrict__ Ws,
                          unsigned short* __restrict__ WnT,
                          unsigned short* __restrict__ WgT, unsigned short* __restrict__ WvT,
                          int* __restrict__ deg, int* __restrict__ gctr) {
    const int b = blockIdx.x;
    if (b == 0 && threadIdx.x == 0) *gctr = 0;
    if (b < NB_PREP) {
        const int i = b * 256 + threadIdx.x;
        if (i < 4 * D * D) {
            const int m = i >> 12, col = (i >> 6) & 63, k = i & 63;
            const float* W = (m == 0) ? Ws : (m == 1) ? Wk : (m == 2) ? Wq : Wv;
            WnT[i] = (unsigned short)f2bf(W[k * D + col]);
        } else {
            const int j = i - 4 * D * D;
            if (j < D * ED) {
                const int c = j >> 5, k = j & 31;
                const int cp = 4 * (c & 15) + (c >> 4);     // permuted column
                const size_t off = (size_t)(D + k) * D + cp;
                WgT[j] = (unsigned short)f2bf(Wk[off] + Wq[off]);
                WvT[j] = (unsigned short)f2bf(Wv[off]);
            }
        }
    } else {
        const int i = (b - NB_PREP) * 256 + threadIdx.x;   // int4 index
        if (i < NN / 4) ((int4v*)deg)[i] = (int4v){0, 0, 0, 0};
    }
}

// Mega-kernel: node MFMA transforms + dst histogram. The histogram's
// atomicAdd RETURN is the edge's rank within its dst run — stored to rank[]
// so the scatter needs NO atomics (its round-trip chain was the 60us cost).
__global__ __launch_bounds__(256, 4)
void node_hist(const float* __restrict__ x, const unsigned short* __restrict__ WnT,
               const float* __restrict__ bk, const float* __restrict__ bq,
               const float* __restrict__ bv, const float* __restrict__ bias,
               unsigned short* __restrict__ kb, unsigned* __restrict__ qv,
               float* __restrict__ out,
               const int* __restrict__ dstI, int* __restrict__ deg,
               unsigned short* __restrict__ rank) {
    const int b = blockIdx.x;
    if (b >= NB_NODE) {
        const int t = (b - NB_NODE) * 256 + threadIdx.x;
        const int e = 4 * t;
        if (e + 4 <= EE) {
            const int4v d4 = __builtin_nontemporal_load((const int4v*)(dstI + e));
            us4v rk;
#pragma unroll
            for (int r = 0; r < 4; ++r)
                rk[r] = (unsigned short)atomicAdd(&deg[d4[r]], 1);
            __builtin_nontemporal_store(rk, (us4v*)(rank + e));
        }
        return;
    }
    const int lane = threadIdx.x & 63;
    const int wid  = b * 4 + (threadIdx.x >> 6);
    if (wid >= NWN) return;
    const int lg = lane >> 4, lr = lane & 15;
    const int n0 = wid * 16;

    const float* xp = x + (size_t)(n0 + lr) * D + 8 * lg;
    const f32x4 x00 = *(const f32x4*)xp;
    const f32x4 x01 = *(const f32x4*)(xp + 4);
    const f32x4 x10 = *(const f32x4*)(xp + 32);
    const f32x4 x11 = *(const f32x4*)(xp + 36);
    bf16x8 af0, af1;
#pragma unroll
    for (int e = 0; e < 4; ++e) {
        af0[e] = f2bf(x00[e]); af0[e + 4] = f2bf(x01[e]);
        af1[e] = f2bf(x10[e]); af1[e + 4] = f2bf(x11[e]);
    }

    f32x4 acc[4], accQ[4];
#pragma unroll
    for (int m = 0; m < 4; ++m) {
        f32x4* A = (m == 2) ? accQ : acc;
#pragma unroll
        for (int h = 0; h < 4; ++h) {
            const bf16x8 b0 = *(const bf16x8*)(WnT + (size_t)(m * D + 16 * h + lr) * D + 8 * lg);
            const bf16x8 b1 = *(const bf16x8*)(WnT + (size_t)(m * D + 16 * h + lr) * D + 32 + 8 * lg);
            A[h] = __builtin_amdgcn_mfma_f32_16x16x32_bf16(af0, b0, (f32x4)(0.f), 0, 0, 0);
            A[h] = __builtin_amdgcn_mfma_f32_16x16x32_bf16(af1, b1, A[h], 0, 0, 0);
        }
        if (m == 0) {
#pragma unroll
            for (int r = 0; r < 4; ++r)
#pragma unroll
                for (int h = 0; h < 4; ++h)
                    out[(size_t)(n0 + 4 * lg + r) * D + 16 * h + lr] = acc[h][r] + bias[16 * h + lr];
        } else if (m == 1) {
#pragma unroll
            for (int r = 0; r < 4; ++r)
#pragma unroll
                for (int h = 0; h < 4; ++h)
                    kb[(size_t)(n0 + 4 * lg + r) * D + 16 * h + lr] =
                        (unsigned short)f2bf(acc[h][r] + bk[16 * h + lr]);
        } else if (m == 3) {
#pragma unroll
            for (int r = 0; r < 4; ++r)
#pragma unroll
                for (int h = 0; h < 4; ++h)
                    qv[(size_t)(n0 + 4 * lg + r) * D + 16 * h + lr] =
                        packqv(accQ[h][r] + bq[16 * h + lr], acc[h][r] + bv[16 * h + lr]);
        }
    }
}

// Exclusive scan with atomic global base (proven). off is NOT consumed later.
__global__ void k_scanA(const int* __restrict__ deg, int* __restrict__ off,
                        int* __restrict__ gctr) {
    __shared__ int s_tmp[256];
    __shared__ int s_base;
    const int t = threadIdx.x, i = blockIdx.x * 256 + t;
    const int v = (i < NN) ? deg[i] : 0;
    s_tmp[t] = v;
    __syncthreads();
    for (int d = 1; d < 256; d <<= 1) {
        const int add = (t >= d) ? s_tmp[t - d] : 0;
        __syncthreads();
        s_tmp[t] += add;
        __syncthreads();
    }
    if (t == 255) s_base = atomicAdd(gctr, s_tmp[255]);
    __syncthreads();
    if (i < NN) off[i] = s_base + s_tmp[t] - v;
}

// Scatter, ATOMIC-FREE: p = off[d] + rank[e]. Pure dataflow — coalesced
// src/dst/rank loads, one L2-hot off[d] gather, one NT 8B store.
__global__ void k_scatter1(const int* __restrict__ srcI, const int* __restrict__ dstI,
                           const unsigned short* __restrict__ rank,
                           const int* __restrict__ off,
                           unsigned long long* __restrict__ rec) {
    const int e = blockIdx.x * 256 + threadIdx.x;
    const int s = srcI[e], d = dstI[e];
    const int p = off[d] + (int)rank[e];
    __builtin_nontemporal_store(
        ((unsigned long long)(unsigned)e << 32) | (unsigned)(s | (d << 16)),
        rec + p);
}

// Edge-parallel aggregation (r13/r16 structure, frozen).
__global__ __launch_bounds__(256, 4)
void agg_sorted(const unsigned* __restrict__ rec, const float* __restrict__ ea,
                const unsigned short* __restrict__ WgT, const unsigned short* __restrict__ WvT,
                const unsigned short* __restrict__ kb, const unsigned* __restrict__ qv,
                float* __restrict__ out) {
    const int lane = threadIdx.x & 63;
    const int wid  = blockIdx.x * 4 + (threadIdx.x >> 6);   // tile id, grid exact
    const int lg = lane >> 4;
    const int lr = lane & 15;
    const int e0 = wid * 64;

    bf16x8 bg[4], bvf[4];
#pragma unroll
    for (int h = 0; h < 4; ++h) {
        bg[h]  = *(const bf16x8*)(WgT + (size_t)(16 * h + lr) * ED + 8 * lg);
        bvf[h] = *(const bf16x8*)(WvT + (size_t)(16 * h + lr) * ED + 8 * lg);
    }

#pragma unroll
    for (int g = 0; g < 4; ++g) {
        const int gb = e0 + 16 * g;
        const uint4v rA = *(const uint4v*)(rec + 2 * (gb + 4 * lg));
        const uint4v rB = *(const uint4v*)(rec + 2 * (gb + 4 * lg) + 4);
        int dR[4], sR[4];
        dR[0] = (int)(rA.x >> 16); sR[0] = (int)(rA.x & 0xFFFFu);
        dR[1] = (int)(rA.z >> 16); sR[1] = (int)(rA.z & 0xFFFFu);
        dR[2] = (int)(rB.x >> 16); sR[2] = (int)(rB.x & 0xFFFFu);
        dR[3] = (int)(rB.z >> 16); sR[3] = (int)(rB.z & 0xFFFFu);

        const unsigned pl = rec[2 * (gb + lr) + 1];
        const float* ap = ea + (size_t)pl * ED + 8 * lg;
        const f32x4 a0 = __builtin_nontemporal_load((const f32x4*)ap);
        const f32x4 a1 = __builtin_nontemporal_load((const f32x4*)(ap + 4));

        // vector gathers: per C-row one uint4 (qv, 16B) + one ushort4 (kb, 8B)
        uint4v qd[4];
        us4v   kd[4];
#pragma unroll
        for (int r = 0; r < 4; ++r) {
            qd[r] = *(const uint4v*)(qv + (size_t)sR[r] * D + 4 * lr);
            kd[r] = *(const us4v*)(kb + (size_t)dR[r] * D + 4 * lr);
        }

        bf16x8 af;
#pragma unroll
        for (int e2 = 0; e2 < 4; ++e2) { af[e2] = f2bf(a0[e2]); af[e2 + 4] = f2bf(a1[e2]); }

        f32x4 accG[4], accV[4];
#pragma unroll
        for (int h = 0; h < 4; ++h) {
            accG[h] = __builtin_amdgcn_mfma_f32_16x16x32_bf16(af, bg[h],  (f32x4)(0.f), 0, 0, 0);
            accV[h] = __builtin_amdgcn_mfma_f32_16x16x32_bf16(af, bvf[h], (f32x4)(0.f), 0, 0, 0);
        }

        // msg[r][h]: edge gb+4lg+r, logical dim 4lr+h
        float msg[4][4];
#pragma unroll
        for (int r = 0; r < 4; ++r)
#pragma unroll
            for (int h = 0; h < 4; ++h) {
                const float z = accG[h][r] + us2f(kd[r][h]) + bflo2f(qd[r][h]);
                const float v = accV[h][r] + bfhi2f(qd[r][h]);
                msg[r][h] = v * __builtin_amdgcn_rcpf(1.0f + __expf(-z));
            }

        bool done[4] = {false, false, false, false};
        while (true) {
            int m0 = 0x7FFFFFFF;
#pragma unroll
            for (int r = 0; r < 4; ++r) m0 = min(m0, done[r] ? 0x7FFFFFFF : dR[r]);
            m0 = min(m0, __shfl_xor(m0, 16, 64));
            m0 = min(m0, __shfl_xor(m0, 32, 64));
            if (m0 == 0x7FFFFFFF) break;          // wave-uniform exit
            float sh[4];
#pragma unroll
            for (int h = 0; h < 4; ++h) {
                float a = 0.f;
#pragma unroll
                for (int r = 0; r < 4; ++r) a += (dR[r] == m0) ? msg[r][h] : 0.f;
                a += __shfl_xor(a, 16, 64);
                a += __shfl_xor(a, 32, 64);
                sh[h] = a;        // every lane: run-total for dim 4*(lane&15)+h
            }
#pragma unroll
            for (int r = 0; r < 4; ++r) done[r] = done[r] || (dR[r] == m0);
            // transpose: lane j takes dim j = 4*(j>>2) + (j&3)
            const int qsrc = lane >> 2;
            const float t0 = __shfl(sh[0], qsrc, 64);
            const float t1 = __shfl(sh[1], qsrc, 64);
            const float t2 = __shfl(sh[2], qsrc, 64);
            const float t3 = __shfl(sh[3], qsrc, 64);
            const int hs = lane & 3;
            const float val = (hs == 0) ? t0 : (hs == 1) ? t1 : (hs == 2) ? t2 : t3;
            // one contiguous 256B wave-atomic per run
            unsafeAtomicAdd(&out[(size_t)m0 * D + lane], val);
        }
    }
}

extern "C" void kernel_launch(void* const* d_in, const int* in_sizes, int n_in,
                              void* d_out, int out_size, void* d_ws, size_t ws_size,
                              hipStream_t stream) {
    const float* x    = (const float*)d_in[0];
    const int*   eidx = (const int*)d_in[1];      // [2, E]: row0=src, row1=dst
    const float* eatt = (const float*)d_in[2];
    const float* Wk   = (const float*)d_in[3];
    const float* bk   = (const float*)d_in[4];
    const float* Wq   = (const float*)d_in[5];
    const float* bq   = (const float*)d_in[6];
    const float* Wv   = (const float*)d_in[7];
    const float* bv   = (const float*)d_in[8];
    const float* Ws   = (const float*)d_in[9];
    const float* bias = (const float*)d_in[10];
    float* out = (float*)d_out;

    // workspace carve (offsets keep 16B alignment)
    char* w = (char*)d_ws;
    unsigned short* kb = (unsigned short*)w;   w += (size_t)NN * D * 2;  // 6.4 MB
    unsigned* qv  = (unsigned*)w;              w += (size_t)NN * D * 4;  // 12.8 MB
    unsigned short* WnT = (unsigned short*)w;  w += 4 * D * D * 2;       // 32 KB
    unsigned short* WgT = (unsigned short*)w;  w += D * ED * 2;          // 4 KB
    unsigned short* WvT = (unsigned short*)w;  w += D * ED * 2;          // 4 KB
    int* deg  = (int*)w;                  w += (size_t)NN * 4;           // 200 KB
    int* gctr = (int*)w;                  w += 16;                       // 16 B
    int* off  = (int*)w;                  w += (size_t)NN * 4;           // 200 KB
    unsigned short* rank = (unsigned short*)w; w += (size_t)EE * 2;      // 1.6 MB
    unsigned long long* rec = (unsigned long long*)w;                    // 6.4 MB

    const int* srcI = eidx;
    const int* dstI = eidx + EE;

    // 1) weight prep + deg/gctr zero
    prep_zero<<<NB_PREP + NB_ZERO, 256, 0, stream>>>(Wk, Wq, Wv, Ws,
                                                     WnT, WgT, WvT, deg, gctr);
    // 2) node transforms + histogram (rank capture)
    node_hist<<<NB_NODE + NB_HIST, 256, 0, stream>>>(x, WnT, bk, bq, bv, bias,
                                                     kb, qv, out, dstI, deg, rank);
    // 3) scan with atomic global base
    k_scanA<<<NB_SCAN, 256, 0, stream>>>(deg, off, gctr);
    // 4) atomic-free scatter into dst-grouped records
    k_scatter1<<<NB_SCAT, 256, 0, stream>>>(srcI, dstI, rank, off, rec);
    // 5) aggregation
    agg_sorted<<<NT64 / 4, 256, 0, stream>>>((const unsigned*)rec, eatt,
                                             WgT, WvT, kb, qv, out);
}

// Round 18
// 148.192 us; speedup vs baseline: 1.9540x; 1.1063x over previous
//
#include <hip/hip_runtime.h>
#include <hip/hip_bf16.h>

#define D 64
#define ED 32
#define NN 50000
#define EE 800000
#define NT64 (EE / 64)   // 12500 64-edge tiles, exact
#define NWN (NN / 16)    // 3125 16-node tiles, exact

#define PREP_N (4 * D * D + D * ED)          // 18432 prep elements
#define NB_PREP ((PREP_N + 255) / 256)       // 72
#define NB_NODE ((NWN + 3) / 4)              // 782
#define NB_SCAN ((NN + 255) / 256)           // 196
#define B_RANK 128
#define EPB (EE / B_RANK)                    // 6250 edges per rank-block
#define NPH 25000                            // nodes per LDS phase
#define LDSW (NPH / 2)                       // 12500 packed u16-pair counters

typedef __attribute__((ext_vector_type(8))) short bf16x8;
typedef __attribute__((ext_vector_type(4))) float f32x4;
typedef __attribute__((ext_vector_type(4))) unsigned uint4v;
typedef __attribute__((ext_vector_type(4))) int int4v;
typedef __attribute__((ext_vector_type(4))) unsigned short us4v;

__device__ __forceinline__ short f2bf(float f) {
    __hip_bfloat16 h = __float2bfloat16(f);
    return *reinterpret_cast<short*>(&h);
}
__device__ __forceinline__ float bfhi2f(unsigned w) { return __uint_as_float(w & 0xFFFF0000u); }
__device__ __forceinline__ float bflo2f(unsigned w) { return __uint_as_float(w << 16); }
__device__ __forceinline__ float us2f(unsigned short u) { return __uint_as_float(((unsigned)u) << 16); }
__device__ __forceinline__ unsigned packqv(float q, float v) {
    return (unsigned)(unsigned short)f2bf(q) | ((unsigned)(unsigned short)f2bf(v) << 16);
}

// Weight prep (WnT natural layout; WgT/WvT column-permuted, r12/13 proven) + gctr zero.
__global__ void prep_w(const float* __restrict__ Wk, const float* __restrict__ Wq,
                       const float* __restrict__ Wv, const float* __restrict__ Ws,
                       unsigned short* __restrict__ WnT,
                       unsigned short* __restrict__ WgT, unsigned short* __restrict__ WvT,
                       int* __restrict__ gctr) {
    if (blockIdx.x == 0 && threadIdx.x == 0) *gctr = 0;
    const int i = blockIdx.x * 256 + threadIdx.x;
    if (i < 4 * D * D) {
        const int m = i >> 12, col = (i >> 6) & 63, k = i & 63;
        const float* W = (m == 0) ? Ws : (m == 1) ? Wk : (m == 2) ? Wq : Wv;
        WnT[i] = (unsigned short)f2bf(W[k * D + col]);
    } else if (i < PREP_N) {
        const int j = i - 4 * D * D;
        const int c = j >> 5, k = j & 31;
        const int cp = 4 * (c & 15) + (c >> 4);     // permuted column
        const size_t off = (size_t)(D + k) * D + cp;
        WgT[j] = (unsigned short)f2bf(Wk[off] + Wq[off]);
        WvT[j] = (unsigned short)f2bf(Wv[off]);
    }
}

// LDS-local per-block ranking: NO global returning atomics. Each block ranks
// its 6250 edges via packed ds_add_rtn counters (2 node-phases x 25000),
// dumping per-block histograms H[b][50000] (u16).
__global__ __launch_bounds__(256)
void k_rank(const int* __restrict__ dstI, unsigned short* __restrict__ lrank,
            unsigned short* __restrict__ H) {
    __shared__ unsigned cnt[LDSW];   // 50 KB
    const int blk = blockIdx.x;
    const int e0 = blk * EPB;
#pragma unroll 1
    for (int ph = 0; ph < 2; ++ph) {
        const int base = ph * NPH;
        for (int j = threadIdx.x; j < LDSW; j += 256) cnt[j] = 0;
        __syncthreads();
        for (int i = threadIdx.x; i < EPB; i += 256) {
            const int d = dstI[e0 + i];
            const unsigned dl = (unsigned)(d - base);
            if (dl < (unsigned)NPH) {
                const unsigned sh = (dl & 1u) * 16u;
                const unsigned old = atomicAdd(&cnt[dl >> 1], 1u << sh);
                lrank[e0 + i] = (unsigned short)((old >> sh) & 0xFFFFu);
            }
        }
        __syncthreads();
        unsigned* H32 = (unsigned*)(H + (size_t)blk * NN + base);
        for (int j = threadIdx.x; j < LDSW; j += 256) H32[j] = cnt[j];
        __syncthreads();
    }
}

// Column scan over the 128 block-histograms (in place H -> cross-block prefix P)
// fused with the proven block-scan + atomic global base -> off[d].
__global__ __launch_bounds__(256)
void k_colscanA(unsigned short* __restrict__ H, int* __restrict__ off,
                int* __restrict__ gctr) {
    __shared__ int s_tmp[256];
    __shared__ int s_base;
    const int t = threadIdx.x, d = blockIdx.x * 256 + t;
    int acc = 0;
    if (d < NN) {
#pragma unroll 8
        for (int b = 0; b < B_RANK; ++b) {
            const int idx = b * NN + d;          // coalesced across threads
            const unsigned short h = H[idx];
            H[idx] = (unsigned short)acc;        // in-place P[b][d]
            acc += h;
        }
    }
    s_tmp[t] = acc;                              // deg[d], never hits memory
    __syncthreads();
    for (int dd = 1; dd < 256; dd <<= 1) {
        const int add = (t >= dd) ? s_tmp[t - dd] : 0;
        __syncthreads();
        s_tmp[t] += add;
        __syncthreads();
    }
    if (t == 255) s_base = atomicAdd(gctr, s_tmp[255]);
    __syncthreads();
    if (d < NN) off[d] = s_base + s_tmp[t] - acc;
}

// Standalone node transforms via MFMA (r17 node half, unchanged math).
__global__ __launch_bounds__(256, 4)
void node_all(const float* __restrict__ x, const unsigned short* __restrict__ WnT,
              const float* __restrict__ bk, const float* __restrict__ bq,
              const float* __restrict__ bv, const float* __restrict__ bias,
              unsigned short* __restrict__ kb, unsigned* __restrict__ qv,
              float* __restrict__ out) {
    const int lane = threadIdx.x & 63;
    const int wid  = blockIdx.x * 4 + (threadIdx.x >> 6);
    if (wid >= NWN) return;
    const int lg = lane >> 4, lr = lane & 15;
    const int n0 = wid * 16;

    const float* xp = x + (size_t)(n0 + lr) * D + 8 * lg;
    const f32x4 x00 = *(const f32x4*)xp;
    const f32x4 x01 = *(const f32x4*)(xp + 4);
    const f32x4 x10 = *(const f32x4*)(xp + 32);
    const f32x4 x11 = *(const f32x4*)(xp + 36);
    bf16x8 af0, af1;
#pragma unroll
    for (int e = 0; e < 4; ++e) {
        af0[e] = f2bf(x00[e]); af0[e + 4] = f2bf(x01[e]);
        af1[e] = f2bf(x10[e]); af1[e + 4] = f2bf(x11[e]);
    }

    f32x4 acc[4], accQ[4];
#pragma unroll
    for (int m = 0; m < 4; ++m) {
        f32x4* A = (m == 2) ? accQ : acc;
#pragma unroll
        for (int h = 0; h < 4; ++h) {
            const bf16x8 b0 = *(const bf16x8*)(WnT + (size_t)(m * D + 16 * h + lr) * D + 8 * lg);
            const bf16x8 b1 = *(const bf16x8*)(WnT + (size_t)(m * D + 16 * h + lr) * D + 32 + 8 * lg);
            A[h] = __builtin_amdgcn_mfma_f32_16x16x32_bf16(af0, b0, (f32x4)(0.f), 0, 0, 0);
            A[h] = __builtin_amdgcn_mfma_f32_16x16x32_bf16(af1, b1, A[h], 0, 0, 0);
        }
        if (m == 0) {
#pragma unroll
            for (int r = 0; r < 4; ++r)
#pragma unroll
                for (int h = 0; h < 4; ++h)
                    out[(size_t)(n0 + 4 * lg + r) * D + 16 * h + lr] = acc[h][r] + bias[16 * h + lr];
        } else if (m == 1) {
#pragma unroll
            for (int r = 0; r < 4; ++r)
#pragma unroll
                for (int h = 0; h < 4; ++h)
                    kb[(size_t)(n0 + 4 * lg + r) * D + 16 * h + lr] =
                        (unsigned short)f2bf(acc[h][r] + bk[16 * h + lr]);
        } else if (m == 3) {
#pragma unroll
            for (int r = 0; r < 4; ++r)
#pragma unroll
                for (int h = 0; h < 4; ++h)
                    qv[(size_t)(n0 + 4 * lg + r) * D + 16 * h + lr] =
                        packqv(accQ[h][r] + bq[16 * h + lr], acc[h][r] + bv[16 * h + lr]);
        }
    }
}

// Atomic-free scatter: p = off[d] + P[e/EPB][d] + lrank[e].
__global__ void k_scatter(const int* __restrict__ srcI, const int* __restrict__ dstI,
                          const unsigned short* __restrict__ lrank,
                          const unsigned short* __restrict__ P,
                          const int* __restrict__ off,
                          unsigned long long* __restrict__ rec) {
    const int e = blockIdx.x * 256 + threadIdx.x;
    const int s = srcI[e], d = dstI[e];
    const int b = e / EPB;
    const int p = off[d] + (int)P[b * NN + d] + (int)lrank[e];
    __builtin_nontemporal_store(
        ((unsigned long long)(unsigned)e << 32) | (unsigned)(s | (d << 16)),
        rec + p);
}

// Edge-parallel aggregation (r13/r17 structure, FROZEN control).
__global__ __launch_bounds__(256, 4)
void agg_sorted(const unsigned* __restrict__ rec, const float* __restrict__ ea,
                const unsigned short* __restrict__ WgT, const unsigned short* __restrict__ WvT,
                const unsigned short* __restrict__ kb, const unsigned* __restrict__ qv,
                float* __restrict__ out) {
    const int lane = threadIdx.x & 63;
    const int wid  = blockIdx.x * 4 + (threadIdx.x >> 6);   // tile id, grid exact
    const int lg = lane >> 4;
    const int lr = lane & 15;
    const int e0 = wid * 64;

    bf16x8 bg[4], bvf[4];
#pragma unroll
    for (int h = 0; h < 4; ++h) {
        bg[h]  = *(const bf16x8*)(WgT + (size_t)(16 * h + lr) * ED + 8 * lg);
        bvf[h] = *(const bf16x8*)(WvT + (size_t)(16 * h + lr) * ED + 8 * lg);
    }

#pragma unroll
    for (int g = 0; g < 4; ++g) {
        const int gb = e0 + 16 * g;
        const uint4v rA = *(const uint4v*)(rec + 2 * (gb + 4 * lg));
        const uint4v rB = *(const uint4v*)(rec + 2 * (gb + 4 * lg) + 4);
        int dR[4], sR[4];
        dR[0] = (int)(rA.x >> 16); sR[0] = (int)(rA.x & 0xFFFFu);
        dR[1] = (int)(rA.z >> 16); sR[1] = (int)(rA.z & 0xFFFFu);
        dR[2] = (int)(rB.x >> 16); sR[2] = (int)(rB.x & 0xFFFFu);
        dR[3] = (int)(rB.z >> 16); sR[3] = (int)(rB.z & 0xFFFFu);

        const unsigned pl = rec[2 * (gb + lr) + 1];
        const float* ap = ea + (size_t)pl * ED + 8 * lg;
        const f32x4 a0 = __builtin_nontemporal_load((const f32x4*)ap);
        const f32x4 a1 = __builtin_nontemporal_load((const f32x4*)(ap + 4));

        // vector gathers: per C-row one uint4 (qv, 16B) + one ushort4 (kb, 8B)
        uint4v qd[4];
        us4v   kd[4];
#pragma unroll
        for (int r = 0; r < 4; ++r) {
            qd[r] = *(const uint4v*)(qv + (size_t)sR[r] * D + 4 * lr);
            kd[r] = *(const us4v*)(kb + (size_t)dR[r] * D + 4 * lr);
        }

        bf16x8 af;
#pragma unroll
        for (int e2 = 0; e2 < 4; ++e2) { af[e2] = f2bf(a0[e2]); af[e2 + 4] = f2bf(a1[e2]); }

        f32x4 accG[4], accV[4];
#pragma unroll
        for (int h = 0; h < 4; ++h) {
            accG[h] = __builtin_amdgcn_mfma_f32_16x16x32_bf16(af, bg[h],  (f32x4)(0.f), 0, 0, 0);
            accV[h] = __builtin_amdgcn_mfma_f32_16x16x32_bf16(af, bvf[h], (f32x4)(0.f), 0, 0, 0);
        }

        // msg[r][h]: edge gb+4lg+r, logical dim 4lr+h
        float msg[4][4];
#pragma unroll
        for (int r = 0; r < 4; ++r)
#pragma unroll
            for (int h = 0; h < 4; ++h) {
                const float z = accG[h][r] + us2f(kd[r][h]) + bflo2f(qd[r][h]);
                const float v = accV[h][r] + bfhi2f(qd[r][h]);
                msg[r][h] = v * __builtin_amdgcn_rcpf(1.0f + __expf(-z));
            }

        bool done[4] = {false, false, false, false};
        while (true) {
            int m0 = 0x7FFFFFFF;
#pragma unroll
            for (int r = 0; r < 4; ++r) m0 = min(m0, done[r] ? 0x7FFFFFFF : dR[r]);
            m0 = min(m0, __shfl_xor(m0, 16, 64));
            m0 = min(m0, __shfl_xor(m0, 32, 64));
            if (m0 == 0x7FFFFFFF) break;          // wave-uniform exit
            float sh[4];
#pragma unroll
            for (int h = 0; h < 4; ++h) {
                float a = 0.f;
#pragma unroll
                for (int r = 0; r < 4; ++r) a += (dR[r] == m0) ? msg[r][h] : 0.f;
                a += __shfl_xor(a, 16, 64);
                a += __shfl_xor(a, 32, 64);
                sh[h] = a;        // every lane: run-total for dim 4*(lane&15)+h
            }
#pragma unroll
            for (int r = 0; r < 4; ++r) done[r] = done[r] || (dR[r] == m0);
            // transpose: lane j takes dim j = 4*(j>>2) + (j&3)
            const int qsrc = lane >> 2;
            const float t0 = __shfl(sh[0], qsrc, 64);
            const float t1 = __shfl(sh[1], qsrc, 64);
            const float t2 = __shfl(sh[2], qsrc, 64);
            const float t3 = __shfl(sh[3], qsrc, 64);
            const int hs = lane & 3;
            const float val = (hs == 0) ? t0 : (hs == 1) ? t1 : (hs == 2) ? t2 : t3;
            // one contiguous 256B wave-atomic per run
            unsafeAtomicAdd(&out[(size_t)m0 * D + lane], val);
        }
    }
}

extern "C" void kernel_launch(void* const* d_in, const int* in_sizes, int n_in,
                              void* d_out, int out_size, void* d_ws, size_t ws_size,
                              hipStream_t stream) {
    const float* x    = (const float*)d_in[0];
    const int*   eidx = (const int*)d_in[1];      // [2, E]: row0=src, row1=dst
    const float* eatt = (const float*)d_in[2];
    const float* Wk   = (const float*)d_in[3];
    const float* bk   = (const float*)d_in[4];
    const float* Wq   = (const float*)d_in[5];
    const float* bq   = (const float*)d_in[6];
    const float* Wv   = (const float*)d_in[7];
    const float* bv   = (const float*)d_in[8];
    const float* Ws   = (const float*)d_in[9];
    const float* bias = (const float*)d_in[10];
    float* out = (float*)d_out;

    // workspace carve (offsets keep 16B alignment); total ~40.3 MB
    char* w = (char*)d_ws;
    unsigned short* kb = (unsigned short*)w;   w += (size_t)NN * D * 2;  // 6.4 MB
    unsigned* qv  = (unsigned*)w;              w += (size_t)NN * D * 4;  // 12.8 MB
    unsigned short* WnT = (unsigned short*)w;  w += 4 * D * D * 2;       // 32 KB
    unsigned short* WgT = (unsigned short*)w;  w += D * ED * 2;          // 4 KB
    unsigned short* WvT = (unsigned short*)w;  w += D * ED * 2;          // 4 KB
    int* gctr = (int*)w;                       w += 16;                  // 16 B
    int* off  = (int*)w;                       w += (size_t)NN * 4;      // 200 KB
    unsigned short* lrank = (unsigned short*)w; w += (size_t)EE * 2;     // 1.6 MB
    unsigned short* H = (unsigned short*)w;    w += (size_t)B_RANK * NN * 2; // 12.8 MB
    unsigned long long* rec = (unsigned long long*)w;                    // 6.4 MB

    const int* srcI = eidx;
    const int* dstI = eidx + EE;

    // 1) weight prep + gctr zero
    prep_w<<<NB_PREP, 256, 0, stream>>>(Wk, Wq, Wv, Ws, WnT, WgT, WvT, gctr);
    // 2) LDS-local per-block ranking (no global returning atomics)
    k_rank<<<B_RANK, 256, 0, stream>>>(dstI, lrank, H);
    // 3) column scan (H -> P in place) + block scan + atomic base -> off
    k_colscanA<<<NB_SCAN, 256, 0, stream>>>(H, off, gctr);
    // 4) node transforms (independent of 2-3)
    node_all<<<NB_NODE, 256, 0, stream>>>(x, WnT, bk, bq, bv, bias, kb, qv, out);
    // 5) atomic-free scatter into dst-grouped records
    k_scatter<<<EE / 256, 256, 0, stream>>>(srcI, dstI, lrank, H, off, rec);
    // 6) aggregation (frozen control)
    agg_sorted<<<NT64 / 4, 256, 0, stream>>>((const unsigned*)rec, eatt,
                                             WgT, WvT, kb, qv, out);
}

// Round 19
// 134.921 us; speedup vs baseline: 2.1462x; 1.0984x over previous
//
#include <hip/hip_runtime.h>
#include <hip/hip_bf16.h>

#define D 64
#define ED 32
#define NN 50000
#define EE 800000
#define NT64 (EE / 64)   // 12500 64-edge tiles, exact
#define NWN (NN / 16)    // 3125 16-node tiles, exact

#define PREP_N (4 * D * D + D * ED)          // 18432 prep elements
#define NB_PREP ((PREP_N + 255) / 256)       // 72
#define NB_NODE ((NWN + 3) / 4)              // 782
#define NB_SCAN ((NN + 255) / 256)           // 196
#define B_RANK 128
#define EPB (EE / B_RANK)                    // 6250 edges per rank-block
#define NPH 25000                            // nodes per LDS phase
#define LDSW (NPH / 2)                       // 12500 packed u16-pair counters

typedef __attribute__((ext_vector_type(8))) short bf16x8;
typedef __attribute__((ext_vector_type(4))) float f32x4;
typedef __attribute__((ext_vector_type(4))) unsigned uint4v;
typedef __attribute__((ext_vector_type(4))) int int4v;
typedef __attribute__((ext_vector_type(4))) unsigned short us4v;

__device__ __forceinline__ short f2bf(float f) {
    __hip_bfloat16 h = __float2bfloat16(f);
    return *reinterpret_cast<short*>(&h);
}
__device__ __forceinline__ float bfhi2f(unsigned w) { return __uint_as_float(w & 0xFFFF0000u); }
__device__ __forceinline__ float bflo2f(unsigned w) { return __uint_as_float(w << 16); }
__device__ __forceinline__ float us2f(unsigned short u) { return __uint_as_float(((unsigned)u) << 16); }
__device__ __forceinline__ unsigned packqv(float q, float v) {
    return (unsigned)(unsigned short)f2bf(q) | ((unsigned)(unsigned short)f2bf(v) << 16);
}

// Weight prep (WnT natural layout; WgT/WvT column-permuted) + gctr zero.
__global__ void prep_w(const float* __restrict__ Wk, const float* __restrict__ Wq,
                       const float* __restrict__ Wv, const float* __restrict__ Ws,
                       unsigned short* __restrict__ WnT,
                       unsigned short* __restrict__ WgT, unsigned short* __restrict__ WvT,
                       int* __restrict__ gctr) {
    if (blockIdx.x == 0 && threadIdx.x == 0) *gctr = 0;
    const int i = blockIdx.x * 256 + threadIdx.x;
    if (i < 4 * D * D) {
        const int m = i >> 12, col = (i >> 6) & 63, k = i & 63;
        const float* W = (m == 0) ? Ws : (m == 1) ? Wk : (m == 2) ? Wq : Wv;
        WnT[i] = (unsigned short)f2bf(W[k * D + col]);
    } else if (i < PREP_N) {
        const int j = i - 4 * D * D;
        const int c = j >> 5, k = j & 31;
        const int cp = 4 * (c & 15) + (c >> 4);     // permuted column
        const size_t off = (size_t)(D + k) * D + cp;
        WgT[j] = (unsigned short)f2bf(Wk[off] + Wq[off]);
        WvT[j] = (unsigned short)f2bf(Wv[off]);
    }
}

// MERGED: LDS-local per-block ranking (blocks 0..127) + MFMA node transforms
// (blocks 128..909). The two are independent; merging overlaps ~25us of rank
// with ~15us of node work that previously ran serially on the stream.
__global__ __launch_bounds__(256, 3)
void rank_node(const int* __restrict__ dstI,
               unsigned short* __restrict__ lrank, unsigned short* __restrict__ H,
               const float* __restrict__ x, const unsigned short* __restrict__ WnT,
               const float* __restrict__ bk, const float* __restrict__ bq,
               const float* __restrict__ bv, const float* __restrict__ bias,
               unsigned short* __restrict__ kb, unsigned* __restrict__ qv,
               float* __restrict__ out) {
    __shared__ unsigned cnt[LDSW];   // 50 KB (rank blocks only; caps 3 blk/CU)
    const int blk = blockIdx.x;
    if (blk < B_RANK) {
        // ---- rank: 6250 edges, 2 node-phases of packed LDS counters ----
        const int e0 = blk * EPB;
#pragma unroll 1
        for (int ph = 0; ph < 2; ++ph) {
            const int base = ph * NPH;
            for (int j = threadIdx.x; j < LDSW; j += 256) cnt[j] = 0;
            __syncthreads();
            for (int i = threadIdx.x; i < EPB; i += 256) {
                const int d = dstI[e0 + i];
                const unsigned dl = (unsigned)(d - base);
                if (dl < (unsigned)NPH) {
                    const unsigned sh = (dl & 1u) * 16u;
                    const unsigned old = atomicAdd(&cnt[dl >> 1], 1u << sh);
                    lrank[e0 + i] = (unsigned short)((old >> sh) & 0xFFFFu);
                }
            }
            __syncthreads();
            unsigned* H32 = (unsigned*)(H + (size_t)blk * NN + base);
            for (int j = threadIdx.x; j < LDSW; j += 256) H32[j] = cnt[j];
            __syncthreads();
        }
        return;
    }
    // ---- node transforms: 16 nodes per wave ----
    const int lane = threadIdx.x & 63;
    const int wid  = (blk - B_RANK) * 4 + (threadIdx.x >> 6);
    if (wid >= NWN) return;
    const int lg = lane >> 4, lr = lane & 15;
    const int n0 = wid * 16;

    const float* xp = x + (size_t)(n0 + lr) * D + 8 * lg;
    const f32x4 x00 = *(const f32x4*)xp;
    const f32x4 x01 = *(const f32x4*)(xp + 4);
    const f32x4 x10 = *(const f32x4*)(xp + 32);
    const f32x4 x11 = *(const f32x4*)(xp + 36);
    bf16x8 af0, af1;
#pragma unroll
    for (int e = 0; e < 4; ++e) {
        af0[e] = f2bf(x00[e]); af0[e + 4] = f2bf(x01[e]);
        af1[e] = f2bf(x10[e]); af1[e + 4] = f2bf(x11[e]);
    }

    f32x4 acc[4], accQ[4];
#pragma unroll
    for (int m = 0; m < 4; ++m) {
        f32x4* A = (m == 2) ? accQ : acc;
#pragma unroll
        for (int h = 0; h < 4; ++h) {
            const bf16x8 b0 = *(const bf16x8*)(WnT + (size_t)(m * D + 16 * h + lr) * D + 8 * lg);
            const bf16x8 b1 = *(const bf16x8*)(WnT + (size_t)(m * D + 16 * h + lr) * D + 32 + 8 * lg);
            A[h] = __builtin_amdgcn_mfma_f32_16x16x32_bf16(af0, b0, (f32x4)(0.f), 0, 0, 0);
            A[h] = __builtin_amdgcn_mfma_f32_16x16x32_bf16(af1, b1, A[h], 0, 0, 0);
        }
        if (m == 0) {
#pragma unroll
            for (int r = 0; r < 4; ++r)
#pragma unroll
                for (int h = 0; h < 4; ++h)
                    out[(size_t)(n0 + 4 * lg + r) * D + 16 * h + lr] = acc[h][r] + bias[16 * h + lr];
        } else if (m == 1) {
#pragma unroll
            for (int r = 0; r < 4; ++r)
#pragma unroll
                for (int h = 0; h < 4; ++h)
                    kb[(size_t)(n0 + 4 * lg + r) * D + 16 * h + lr] =
                        (unsigned short)f2bf(acc[h][r] + bk[16 * h + lr]);
        } else if (m == 3) {
#pragma unroll
            for (int r = 0; r < 4; ++r)
#pragma unroll
                for (int h = 0; h < 4; ++h)
                    qv[(size_t)(n0 + 4 * lg + r) * D + 16 * h + lr] =
                        packqv(accQ[h][r] + bq[16 * h + lr], acc[h][r] + bv[16 * h + lr]);
        }
    }
}

// Column scan over the 128 block-histograms (in place H -> cross-block prefix P)
// fused with block scan + atomic global base -> off[d].
__global__ __launch_bounds__(256)
void k_colscanA(unsigned short* __restrict__ H, int* __restrict__ off,
                int* __restrict__ gctr) {
    __shared__ int s_tmp[256];
    __shared__ int s_base;
    const int t = threadIdx.x, d = blockIdx.x * 256 + t;
    int acc = 0;
    if (d < NN) {
#pragma unroll 8
        for (int b = 0; b < B_RANK; ++b) {
            const int idx = b * NN + d;          // coalesced across threads
            const unsigned short h = H[idx];
            H[idx] = (unsigned short)acc;        // in-place P[b][d]
            acc += h;
        }
    }
    s_tmp[t] = acc;
    __syncthreads();
    for (int dd = 1; dd < 256; dd <<= 1) {
        const int add = (t >= dd) ? s_tmp[t - dd] : 0;
        __syncthreads();
        s_tmp[t] += add;
        __syncthreads();
    }
    if (t == 255) s_base = atomicAdd(gctr, s_tmp[255]);
    __syncthreads();
    if (d < NN) off[d] = s_base + s_tmp[t] - acc;
}

// Atomic-free scatter: p = off[d] + P[e/EPB][d] + lrank[e].
__global__ void k_scatter(const int* __restrict__ srcI, const int* __restrict__ dstI,
                          const unsigned short* __restrict__ lrank,
                          const unsigned short* __restrict__ P,
                          const int* __restrict__ off,
                          unsigned long long* __restrict__ rec) {
    const int e = blockIdx.x * 256 + threadIdx.x;
    const int s = srcI[e], d = dstI[e];
    const int b = e / EPB;
    const int p = off[d] + (int)P[b * NN + d] + (int)lrank[e];
    __builtin_nontemporal_store(
        ((unsigned long long)(unsigned)e << 32) | (unsigned)(s | (d << 16)),
        rec + p);
}

// Edge-parallel aggregation (FROZEN control).
__global__ __launch_bounds__(256, 4)
void agg_sorted(const unsigned* __restrict__ rec, const float* __restrict__ ea,
                const unsigned short* __restrict__ WgT, const unsigned short* __restrict__ WvT,
                const unsigned short* __restrict__ kb, const unsigned* __restrict__ qv,
                float* __restrict__ out) {
    const int lane = threadIdx.x & 63;
    const int wid  = blockIdx.x * 4 + (threadIdx.x >> 6);   // tile id, grid exact
    const int lg = lane >> 4;
    const int lr = lane & 15;
    const int e0 = wid * 64;

    bf16x8 bg[4], bvf[4];
#pragma unroll
    for (int h = 0; h < 4; ++h) {
        bg[h]  = *(const bf16x8*)(WgT + (size_t)(16 * h + lr) * ED + 8 * lg);
        bvf[h] = *(const bf16x8*)(WvT + (size_t)(16 * h + lr) * ED + 8 * lg);
    }

#pragma unroll
    for (int g = 0; g < 4; ++g) {
        const int gb = e0 + 16 * g;
        const uint4v rA = *(const uint4v*)(rec + 2 * (gb + 4 * lg));
        const uint4v rB = *(const uint4v*)(rec + 2 * (gb + 4 * lg) + 4);
        int dR[4], sR[4];
        dR[0] = (int)(rA.x >> 16); sR[0] = (int)(rA.x & 0xFFFFu);
        dR[1] = (int)(rA.z >> 16); sR[1] = (int)(rA.z & 0xFFFFu);
        dR[2] = (int)(rB.x >> 16); sR[2] = (int)(rB.x & 0xFFFFu);
        dR[3] = (int)(rB.z >> 16); sR[3] = (int)(rB.z & 0xFFFFu);

        const unsigned pl = rec[2 * (gb + lr) + 1];
        const float* ap = ea + (size_t)pl * ED + 8 * lg;
        const f32x4 a0 = __builtin_nontemporal_load((const f32x4*)ap);
        const f32x4 a1 = __builtin_nontemporal_load((const f32x4*)(ap + 4));

        // vector gathers: per C-row one uint4 (qv, 16B) + one ushort4 (kb, 8B)
        uint4v qd[4];
        us4v   kd[4];
#pragma unroll
        for (int r = 0; r < 4; ++r) {
            qd[r] = *(const uint4v*)(qv + (size_t)sR[r] * D + 4 * lr);
            kd[r] = *(const us4v*)(kb + (size_t)dR[r] * D + 4 * lr);
        }

        bf16x8 af;
#pragma unroll
        for (int e2 = 0; e2 < 4; ++e2) { af[e2] = f2bf(a0[e2]); af[e2 + 4] = f2bf(a1[e2]); }

        f32x4 accG[4], accV[4];
#pragma unroll
        for (int h = 0; h < 4; ++h) {
            accG[h] = __builtin_amdgcn_mfma_f32_16x16x32_bf16(af, bg[h],  (f32x4)(0.f), 0, 0, 0);
            accV[h] = __builtin_amdgcn_mfma_f32_16x16x32_bf16(af, bvf[h], (f32x4)(0.f), 0, 0, 0);
        }

        // msg[r][h]: edge gb+4lg+r, logical dim 4lr+h
        float msg[4][4];
#pragma unroll
        for (int r = 0; r < 4; ++r)
#pragma unroll
            for (int h = 0; h < 4; ++h) {
                const float z = accG[h][r] + us2f(kd[r][h]) + bflo2f(qd[r][h]);
                const float v = accV[h][r] + bfhi2f(qd[r][h]);
                msg[r][h] = v * __builtin_amdgcn_rcpf(1.0f + __expf(-z));
            }

        bool done[4] = {false, false, false, false};
        while (true) {
            int m0 = 0x7FFFFFFF;
#pragma unroll
            for (int r = 0; r < 4; ++r) m0 = min(m0, done[r] ? 0x7FFFFFFF : dR[r]);
            m0 = min(m0, __shfl_xor(m0, 16, 64));
            m0 = min(m0, __shfl_xor(m0, 32, 64));
            if (m0 == 0x7FFFFFFF) break;          // wave-uniform exit
            float sh[4];
#pragma unroll
            for (int h = 0; h < 4; ++h) {
                float a = 0.f;
#pragma unroll
                for (int r = 0; r < 4; ++r) a += (dR[r] == m0) ? msg[r][h] : 0.f;
                a += __shfl_xor(a, 16, 64);
                a += __shfl_xor(a, 32, 64);
                sh[h] = a;        // every lane: run-total for dim 4*(lane&15)+h
            }
#pragma unroll
            for (int r = 0; r < 4; ++r) done[r] = done[r] || (dR[r] == m0);
            // transpose: lane j takes dim j = 4*(j>>2) + (j&3)
            const int qsrc = lane >> 2;
            const float t0 = __shfl(sh[0], qsrc, 64);
            const float t1 = __shfl(sh[1], qsrc, 64);
            const float t2 = __shfl(sh[2], qsrc, 64);
            const float t3 = __shfl(sh[3], qsrc, 64);
            const int hs = lane & 3;
            const float val = (hs == 0) ? t0 : (hs == 1) ? t1 : (hs == 2) ? t2 : t3;
            // one contiguous 256B wave-atomic per run
            unsafeAtomicAdd(&out[(size_t)m0 * D + lane], val);
        }
    }
}

extern "C" void kernel_launch(void* const* d_in, const int* in_sizes, int n_in,
                              void* d_out, int out_size, void* d_ws, size_t ws_size,
                              hipStream_t stream) {
    const float* x    = (const float*)d_in[0];
    const int*   eidx = (const int*)d_in[1];      // [2, E]: row0=src, row1=dst
    const float* eatt = (const float*)d_in[2];
    const float* Wk   = (const float*)d_in[3];
    const float* bk   = (const float*)d_in[4];
    const float* Wq   = (const float*)d_in[5];
    const float* bq   = (const float*)d_in[6];
    const float* Wv   = (const float*)d_in[7];
    const float* bv   = (const float*)d_in[8];
    const float* Ws   = (const float*)d_in[9];
    const float* bias = (const float*)d_in[10];
    float* out = (float*)d_out;

    // workspace carve (offsets keep 16B alignment); total ~40.3 MB
    char* w = (char*)d_ws;
    unsigned short* kb = (unsigned short*)w;   w += (size_t)NN * D * 2;  // 6.4 MB
    unsigned* qv  = (unsigned*)w;              w += (size_t)NN * D * 4;  // 12.8 MB
    unsigned short* WnT = (unsigned short*)w;  w += 4 * D * D * 2;       // 32 KB
    unsigned short* WgT = (unsigned short*)w;  w += D * ED * 2;          // 4 KB
    unsigned short* WvT = (unsigned short*)w;  w += D * ED * 2;          // 4 KB
    int* gctr = (int*)w;                       w += 16;                  // 16 B
    int* off  = (int*)w;                       w += (size_t)NN * 4;      // 200 KB
    unsigned short* lrank = (unsigned short*)w; w += (size_t)EE * 2;     // 1.6 MB
    unsigned short* H = (unsigned short*)w;    w += (size_t)B_RANK * NN * 2; // 12.8 MB
    unsigned long long* rec = (unsigned long long*)w;                    // 6.4 MB

    const int* srcI = eidx;
    const int* dstI = eidx + EE;

    // 1) weight prep + gctr zero
    prep_w<<<NB_PREP, 256, 0, stream>>>(Wk, Wq, Wv, Ws, WnT, WgT, WvT, gctr);
    // 2) MERGED rank (128 blocks) + node transforms (782 blocks): independent
    //    work overlapped in one dispatch
    rank_node<<<B_RANK + NB_NODE, 256, 0, stream>>>(dstI, lrank, H,
                                                    x, WnT, bk, bq, bv, bias,
                                                    kb, qv, out);
    // 3) column scan (H -> P in place) + block scan + atomic base -> off
    k_colscanA<<<NB_SCAN, 256, 0, stream>>>(H, off, gctr);
    // 4) atomic-free scatter into dst-grouped records
    k_scatter<<<EE / 256, 256, 0, stream>>>(srcI, dstI, lrank, H, off, rec);
    // 5) aggregation (frozen control)
    agg_sorted<<<NT64 / 4, 256, 0, stream>>>((const unsigned*)rec, eatt,
                                             WgT, WvT, kb, qv, out);
}